// Round 3
// baseline (1477.173 us; speedup 1.0000x reference)
//
#include <hip/hip_runtime.h>
#include <hip/hip_bf16.h>
#include <math.h>

// Problem constants
#define BB 4
#define SS 1024
#define DD 1024
#define ENCS 512
#define DI 2048
#define DFF 4096
#define DFE 2048
#define NA 2
#define NB 6
#define NE 8
#define NH 16
#define NTOK (BB*SS)   // 4096
#define W1SZ ((long)DD*DFE)   // elems per expert W1 (= W2)

typedef unsigned short u16;
typedef __bf16 bfrag __attribute__((ext_vector_type(8)));
typedef float  ffrag __attribute__((ext_vector_type(4)));

// ---------------------------------------------------------------------------
// helpers
// ---------------------------------------------------------------------------
__device__ __forceinline__ float gelu_f(float x) {
    const float c = 0.7978845608028654f;
    float t = tanhf(c * (x + 0.044715f * x * x * x));
    return 0.5f * x * (1.f + t);
}

__device__ __forceinline__ u16 f2bf(float f) {
    unsigned u = __float_as_uint(f);
    u += 0x7fffu + ((u >> 16) & 1u);   // RNE
    return (u16)(u >> 16);
}

__device__ __forceinline__ void split_bf(float v, u16& hi, u16& lo) {
    hi = f2bf(v);
    float hf = __uint_as_float((unsigned)hi << 16);
    lo = f2bf(v - hf);
}

typedef const __attribute__((address_space(1))) unsigned int* gas_t;
typedef __attribute__((address_space(3))) unsigned int* las_t;
__device__ __forceinline__ void gload16(const u16* g, u16* l) {
    __builtin_amdgcn_global_load_lds((gas_t)g, (las_t)l, 16, 0, 0);
}

// LDS fragment address in a 64-col bf16 tile with 16B-block XOR swizzle
__device__ __forceinline__ int flds(int row, int p) {
    return row * 64 + (((p ^ (row & 7)) & 7) << 3);
}

// ---------------------------------------------------------------------------
// MFMA bf16 GEMM: C[M,N] = A[M,K] @ Bt[N,K]^T (128x128 tile, BK=32)
// Depth-3 prefetch ring: 3 LDS buffers, counted vmcnt(8/4/0), raw barriers.
// ---------------------------------------------------------------------------
__global__ __launch_bounds__(256) void gemm_mfma(
    const u16* __restrict__ A, const u16* __restrict__ Bt,
    float* __restrict__ Cf, u16* __restrict__ Ch,
    int M, int N, int K,
    long sAb, long sBb, long sCb,
    const float* __restrict__ bias, const float* __restrict__ res,
    const float* __restrict__ rowscale, int rs_stride,
    int accum, int do_gelu)
{
    __shared__ u16 As[3][4096];
    __shared__ u16 Bs[3][4096];
    const int tid = threadIdx.x;
    const int w = tid >> 6, l = tid & 63;
    const int wm = w >> 1, wn = w & 1;
    const int bz = blockIdx.z;
    A  += (long)bz * sAb;
    Bt += (long)bz * sBb;
    const int m0 = blockIdx.y * 128, n0 = blockIdx.x * 128;

    const int c0 = 2 * w, c1 = c0 + 1;
    const int rl0 = c0 * 16 + (l >> 2), rl1 = c1 * 16 + (l >> 2);
    const int p = l & 3;
    const int gb0 = p ^ ((rl0 ^ (rl0 >> 2)) & 3);
    const int gb1 = p ^ ((rl1 ^ (rl1 >> 2)) & 3);
    const u16* gA0 = A  + (long)(m0 + rl0) * K + gb0 * 8;
    const u16* gA1 = A  + (long)(m0 + rl1) * K + gb1 * 8;
    const u16* gB0 = Bt + (long)(n0 + rl0) * K + gb0 * 8;
    const u16* gB1 = Bt + (long)(n0 + rl1) * K + gb1 * 8;
    const int d0 = c0 * 512, d1 = c1 * 512;

    const int q = l >> 4, fr = l & 15;
    int offA[4], offB[4];
    #pragma unroll
    for (int t = 0; t < 4; t++) {
        int ra = wm * 64 + t * 16 + fr;
        offA[t] = ra * 32 + (q ^ ((ra ^ (ra >> 2)) & 3)) * 8;
        int rb = wn * 64 + t * 16 + fr;
        offB[t] = rb * 32 + (q ^ ((rb ^ (rb >> 2)) & 3)) * 8;
    }

    ffrag acc[16];
    #pragma unroll
    for (int i = 0; i < 16; i++) acc[i] = (ffrag){0.f, 0.f, 0.f, 0.f};

    const int nsteps = K >> 5;
    #define STAGE1(bi, k0) do { \
        gload16(gA0 + (k0), &As[bi][d0]); \
        gload16(gA1 + (k0), &As[bi][d1]); \
        gload16(gB0 + (k0), &Bs[bi][d0]); \
        gload16(gB1 + (k0), &Bs[bi][d1]); } while (0)

    STAGE1(0, 0);
    STAGE1(1, 32);
    int cur = 0;
    for (int t = 0; t < nsteps; ++t) {
        int rem = nsteps - 1 - t;
        if (rem >= 2) {
            int nb = cur + 2; if (nb >= 3) nb -= 3;
            STAGE1(nb, (t + 2) << 5);
            asm volatile("s_waitcnt vmcnt(8)" ::: "memory");
        } else if (rem == 1) {
            asm volatile("s_waitcnt vmcnt(4)" ::: "memory");
        } else {
            asm volatile("s_waitcnt vmcnt(0)" ::: "memory");
        }
        __builtin_amdgcn_s_barrier();
        bfrag af[4], bf[4];
        #pragma unroll
        for (int i = 0; i < 4; i++) {
            af[i] = *(const bfrag*)(&As[cur][0] + offA[i]);
            bf[i] = *(const bfrag*)(&Bs[cur][0] + offB[i]);
        }
        #pragma unroll
        for (int mt = 0; mt < 4; mt++)
            #pragma unroll
            for (int nt = 0; nt < 4; nt++)
                acc[mt * 4 + nt] = __builtin_amdgcn_mfma_f32_16x16x32_bf16(
                    af[mt], bf[nt], acc[mt * 4 + nt], 0, 0, 0);
        __builtin_amdgcn_s_barrier();
        cur = (cur == 2) ? 0 : cur + 1;
    }
    #undef STAGE1

    const long cbase = (long)bz * sCb;
    #pragma unroll
    for (int mt = 0; mt < 4; mt++) {
        #pragma unroll
        for (int nt = 0; nt < 4; nt++) {
            ffrag v = acc[mt * 4 + nt];
            int col = n0 + wn * 64 + nt * 16 + fr;
            int row0 = m0 + wm * 64 + mt * 16 + q * 4;
            float bv = bias ? bias[col] : 0.f;
            #pragma unroll
            for (int j = 0; j < 4; j++) {
                int row = row0 + j;
                float x = v[j] + bv;
                if (do_gelu) x = gelu_f(x);
                if (rowscale) x *= rowscale[(long)row * rs_stride];
                long idx = cbase + (long)row * N + col;
                if (res) x += res[(long)row * N + col];
                if (accum) { Cf[idx] += x; }
                else {
                    if (Cf) Cf[idx] = x;
                    if (Ch) Ch[idx] = f2bf(x);
                }
            }
        }
    }
}

// ---------------------------------------------------------------------------
// Fused split-bf16 GEMM: C = Ahi@Bhi^T + Ahi@Blo^T + Alo@Bhi^T in ONE pass.
// Depth-2 (LDS-bound at 64KB); 48 MFMA per K-step amortizes latency.
// ---------------------------------------------------------------------------
__global__ __launch_bounds__(256) void gemm3_mfma(
    const u16* __restrict__ Ahi, const u16* __restrict__ Alo,
    const u16* __restrict__ Bhi, const u16* __restrict__ Blo,
    float* __restrict__ Cf, int M, int N, int K)
{
    __shared__ u16 Ah[2][4096];
    __shared__ u16 Al[2][4096];
    __shared__ u16 Bh[2][4096];
    __shared__ u16 Bl[2][4096];
    const int tid = threadIdx.x;
    const int w = tid >> 6, l = tid & 63;
    const int wm = w >> 1, wn = w & 1;
    const int m0 = blockIdx.y * 128, n0 = blockIdx.x * 128;

    const int c0 = 2 * w, c1 = c0 + 1;
    const int rl0 = c0 * 16 + (l >> 2), rl1 = c1 * 16 + (l >> 2);
    const int p = l & 3;
    const int gb0 = p ^ ((rl0 ^ (rl0 >> 2)) & 3);
    const int gb1 = p ^ ((rl1 ^ (rl1 >> 2)) & 3);
    const long oa0 = (long)(m0 + rl0) * K + gb0 * 8;
    const long oa1 = (long)(m0 + rl1) * K + gb1 * 8;
    const long ob0 = (long)(n0 + rl0) * K + gb0 * 8;
    const long ob1 = (long)(n0 + rl1) * K + gb1 * 8;
    const u16* gAh0 = Ahi + oa0; const u16* gAh1 = Ahi + oa1;
    const u16* gAl0 = Alo + oa0; const u16* gAl1 = Alo + oa1;
    const u16* gBh0 = Bhi + ob0; const u16* gBh1 = Bhi + ob1;
    const u16* gBl0 = Blo + ob0; const u16* gBl1 = Blo + ob1;
    const int d0 = c0 * 512, d1 = c1 * 512;

    const int q = l >> 4, fr = l & 15;
    int offA[4], offB[4];
    #pragma unroll
    for (int t = 0; t < 4; t++) {
        int ra = wm * 64 + t * 16 + fr;
        offA[t] = ra * 32 + (q ^ ((ra ^ (ra >> 2)) & 3)) * 8;
        int rb = wn * 64 + t * 16 + fr;
        offB[t] = rb * 32 + (q ^ ((rb ^ (rb >> 2)) & 3)) * 8;
    }

    ffrag acc[16];
    #pragma unroll
    for (int i = 0; i < 16; i++) acc[i] = (ffrag){0.f, 0.f, 0.f, 0.f};

    const int nsteps = K >> 5;
    #define STAGE3(bi, k0) do { \
        gload16(gAh0 + (k0), &Ah[bi][d0]); \
        gload16(gAh1 + (k0), &Ah[bi][d1]); \
        gload16(gAl0 + (k0), &Al[bi][d0]); \
        gload16(gAl1 + (k0), &Al[bi][d1]); \
        gload16(gBh0 + (k0), &Bh[bi][d0]); \
        gload16(gBh1 + (k0), &Bh[bi][d1]); \
        gload16(gBl0 + (k0), &Bl[bi][d0]); \
        gload16(gBl1 + (k0), &Bl[bi][d1]); } while (0)

    int cur = 0;
    STAGE3(0, 0);
    for (int t = 0; t < nsteps; ++t) {
        if (t + 1 < nsteps) {
            STAGE3(cur ^ 1, (t + 1) << 5);
            asm volatile("s_waitcnt vmcnt(8)" ::: "memory");
        } else {
            asm volatile("s_waitcnt vmcnt(0)" ::: "memory");
        }
        __builtin_amdgcn_s_barrier();
        bfrag ah[4], al[4], bh[4], bl[4];
        #pragma unroll
        for (int i = 0; i < 4; i++) {
            ah[i] = *(const bfrag*)(&Ah[cur][0] + offA[i]);
            al[i] = *(const bfrag*)(&Al[cur][0] + offA[i]);
            bh[i] = *(const bfrag*)(&Bh[cur][0] + offB[i]);
            bl[i] = *(const bfrag*)(&Bl[cur][0] + offB[i]);
        }
        #pragma unroll
        for (int mt = 0; mt < 4; mt++) {
            #pragma unroll
            for (int nt = 0; nt < 4; nt++) {
                ffrag a = acc[mt * 4 + nt];
                a = __builtin_amdgcn_mfma_f32_16x16x32_bf16(ah[mt], bh[nt], a, 0, 0, 0);
                a = __builtin_amdgcn_mfma_f32_16x16x32_bf16(ah[mt], bl[nt], a, 0, 0, 0);
                a = __builtin_amdgcn_mfma_f32_16x16x32_bf16(al[mt], bh[nt], a, 0, 0, 0);
                acc[mt * 4 + nt] = a;
            }
        }
        __builtin_amdgcn_s_barrier();
        cur ^= 1;
    }
    #undef STAGE3

    #pragma unroll
    for (int mt = 0; mt < 4; mt++) {
        #pragma unroll
        for (int nt = 0; nt < 4; nt++) {
            ffrag v = acc[mt * 4 + nt];
            int col = n0 + wn * 64 + nt * 16 + fr;
            int row0 = m0 + wm * 64 + mt * 16 + q * 4;
            #pragma unroll
            for (int j = 0; j < 4; j++)
                Cf[(long)(row0 + j) * N + col] = v[j];
        }
    }
}

static inline void ggemm(hipStream_t st, const u16* A, const u16* Bt,
    float* Cf, u16* Ch, int M, int N, int K, int batch,
    long sA, long sB, long sC,
    const float* bias, const float* res, const float* rs, int rss,
    int accum, int gelu)
{
    dim3 g(N / 128, M / 128, batch), b(256);
    gemm_mfma<<<g, b, 0, st>>>(A, Bt, Cf, Ch, M, N, K, sA, sB, sC,
                               bias, res, rs, rss, accum, gelu);
}

static inline void ggemm3(hipStream_t st, const u16* Ahi, const u16* Alo,
    const u16* Bhi, const u16* Blo, float* Cf, int M, int N, int K)
{
    dim3 g(N / 128, M / 128, 1), b(256);
    gemm3_mfma<<<g, b, 0, st>>>(Ahi, Alo, Bhi, Blo, Cf, M, N, K);
}

// ---------------------------------------------------------------------------
// Sparse MoE FFN, batched across ALL experts in z. Depth-3 prefetch ring.
// ---------------------------------------------------------------------------
__global__ __launch_bounds__(256) void moe_w1(
    const u16* __restrict__ Xa, const u16* __restrict__ Xb,
    const u16* __restrict__ W1a, const u16* __restrict__ W1b,
    u16* __restrict__ ffp,
    const int* __restrict__ idxAll, const int* __restrict__ cntAll,
    const int* __restrict__ offAll, int N, int K)
{
    const int z = blockIdx.z;
    const int m0 = blockIdx.y * 128;
    if (m0 >= cntAll[z]) return;
    const int* idx = idxAll + z * NTOK;
    const u16* X  = (z < NA) ? (Xa + (long)z * NTOK * DD) : Xb;
    const u16* Wt = (z < 4) ? (W1a + (long)z * W1SZ) : (W1b + (long)(z - 4) * W1SZ);
    u16* ff = ffp + (long)offAll[z] * N;

    __shared__ u16 As[3][4096];
    __shared__ u16 Bs[3][4096];
    const int tid = threadIdx.x;
    const int w = tid >> 6, l = tid & 63;
    const int wm = w >> 1, wn = w & 1;
    const int n0 = blockIdx.x * 128;
    const int c0 = 2 * w, c1 = c0 + 1;
    const int rl0 = c0 * 16 + (l >> 2), rl1 = c1 * 16 + (l >> 2);
    const int p = l & 3;
    const int gb0 = p ^ ((rl0 ^ (rl0 >> 2)) & 3);
    const int gb1 = p ^ ((rl1 ^ (rl1 >> 2)) & 3);
    const int t0 = idx[m0 + rl0], t1 = idx[m0 + rl1];
    const u16* gA0 = X + (long)t0 * K + gb0 * 8;
    const u16* gA1 = X + (long)t1 * K + gb1 * 8;
    const u16* gB0 = Wt + (long)(n0 + rl0) * K + gb0 * 8;
    const u16* gB1 = Wt + (long)(n0 + rl1) * K + gb1 * 8;
    const int d0 = c0 * 512, d1 = c1 * 512;
    const int q = l >> 4, fr = l & 15;
    int offA[4], offB[4];
    #pragma unroll
    for (int t = 0; t < 4; t++) {
        int ra = wm * 64 + t * 16 + fr;
        offA[t] = ra * 32 + (q ^ ((ra ^ (ra >> 2)) & 3)) * 8;
        int rb = wn * 64 + t * 16 + fr;
        offB[t] = rb * 32 + (q ^ ((rb ^ (rb >> 2)) & 3)) * 8;
    }
    ffrag acc[16];
    #pragma unroll
    for (int i = 0; i < 16; i++) acc[i] = (ffrag){0.f, 0.f, 0.f, 0.f};

    const int nsteps = K >> 5;
    #define STAGEM(bi, k0) do { \
        gload16(gA0 + (k0), &As[bi][d0]); \
        gload16(gA1 + (k0), &As[bi][d1]); \
        gload16(gB0 + (k0), &Bs[bi][d0]); \
        gload16(gB1 + (k0), &Bs[bi][d1]); } while (0)

    STAGEM(0, 0);
    STAGEM(1, 32);
    int cur = 0;
    for (int t = 0; t < nsteps; ++t) {
        int rem = nsteps - 1 - t;
        if (rem >= 2) {
            int nb = cur + 2; if (nb >= 3) nb -= 3;
            STAGEM(nb, (t + 2) << 5);
            asm volatile("s_waitcnt vmcnt(8)" ::: "memory");
        } else if (rem == 1) {
            asm volatile("s_waitcnt vmcnt(4)" ::: "memory");
        } else {
            asm volatile("s_waitcnt vmcnt(0)" ::: "memory");
        }
        __builtin_amdgcn_s_barrier();
        bfrag af[4], bf[4];
        #pragma unroll
        for (int i = 0; i < 4; i++) {
            af[i] = *(const bfrag*)(&As[cur][0] + offA[i]);
            bf[i] = *(const bfrag*)(&Bs[cur][0] + offB[i]);
        }
        #pragma unroll
        for (int mt = 0; mt < 4; mt++)
            #pragma unroll
            for (int nt = 0; nt < 4; nt++)
                acc[mt * 4 + nt] = __builtin_amdgcn_mfma_f32_16x16x32_bf16(
                    af[mt], bf[nt], acc[mt * 4 + nt], 0, 0, 0);
        __builtin_amdgcn_s_barrier();
        cur = (cur == 2) ? 0 : cur + 1;
    }
    #undef STAGEM

    #pragma unroll
    for (int mt = 0; mt < 4; mt++)
        #pragma unroll
        for (int nt = 0; nt < 4; nt++) {
            ffrag v = acc[mt * 4 + nt];
            int col = n0 + wn * 64 + nt * 16 + fr;
            int row0 = m0 + wm * 64 + mt * 16 + q * 4;
            #pragma unroll
            for (int j = 0; j < 4; j++)
                ff[(long)(row0 + j) * N + col] = f2bf(gelu_f(v[j]));
        }
}

__global__ __launch_bounds__(256) void moe_w2(
    const u16* __restrict__ ffp,
    const u16* __restrict__ W2a, const u16* __restrict__ W2b,
    float* __restrict__ out,
    const int* __restrict__ idxAll, const float* __restrict__ gvAll,
    const int* __restrict__ cntAll, const int* __restrict__ offAll,
    int N, int K)
{
    const int z = blockIdx.z;
    const int cnt = cntAll[z];
    const int m0 = blockIdx.y * 128;
    if (m0 >= cnt) return;
    const int* idx = idxAll + z * NTOK;
    const float* gval = gvAll + z * NTOK;
    const u16* Aseg = ffp + (long)offAll[z] * K;
    const u16* Wt = (z < 4) ? (W2a + (long)z * W1SZ) : (W2b + (long)(z - 4) * W1SZ);

    __shared__ u16 As[3][4096];
    __shared__ u16 Bs[3][4096];
    const int tid = threadIdx.x;
    const int w = tid >> 6, l = tid & 63;
    const int wm = w >> 1, wn = w & 1;
    const int n0 = blockIdx.x * 128;
    const int c0 = 2 * w, c1 = c0 + 1;
    const int rl0 = c0 * 16 + (l >> 2), rl1 = c1 * 16 + (l >> 2);
    const int p = l & 3;
    const int gb0 = p ^ ((rl0 ^ (rl0 >> 2)) & 3);
    const int gb1 = p ^ ((rl1 ^ (rl1 >> 2)) & 3);
    const u16* gA0 = Aseg + (long)(m0 + rl0) * K + gb0 * 8;
    const u16* gA1 = Aseg + (long)(m0 + rl1) * K + gb1 * 8;
    const u16* gB0 = Wt + (long)(n0 + rl0) * K + gb0 * 8;
    const u16* gB1 = Wt + (long)(n0 + rl1) * K + gb1 * 8;
    const int d0 = c0 * 512, d1 = c1 * 512;
    const int q = l >> 4, fr = l & 15;
    int offA[4], offB[4];
    #pragma unroll
    for (int t = 0; t < 4; t++) {
        int ra = wm * 64 + t * 16 + fr;
        offA[t] = ra * 32 + (q ^ ((ra ^ (ra >> 2)) & 3)) * 8;
        int rb = wn * 64 + t * 16 + fr;
        offB[t] = rb * 32 + (q ^ ((rb ^ (rb >> 2)) & 3)) * 8;
    }
    ffrag acc[16];
    #pragma unroll
    for (int i = 0; i < 16; i++) acc[i] = (ffrag){0.f, 0.f, 0.f, 0.f};

    const int nsteps = K >> 5;
    #define STAGEW(bi, k0) do { \
        gload16(gA0 + (k0), &As[bi][d0]); \
        gload16(gA1 + (k0), &As[bi][d1]); \
        gload16(gB0 + (k0), &Bs[bi][d0]); \
        gload16(gB1 + (k0), &Bs[bi][d1]); } while (0)

    STAGEW(0, 0);
    STAGEW(1, 32);
    int cur = 0;
    for (int t = 0; t < nsteps; ++t) {
        int rem = nsteps - 1 - t;
        if (rem >= 2) {
            int nb = cur + 2; if (nb >= 3) nb -= 3;
            STAGEW(nb, (t + 2) << 5);
            asm volatile("s_waitcnt vmcnt(8)" ::: "memory");
        } else if (rem == 1) {
            asm volatile("s_waitcnt vmcnt(4)" ::: "memory");
        } else {
            asm volatile("s_waitcnt vmcnt(0)" ::: "memory");
        }
        __builtin_amdgcn_s_barrier();
        bfrag af[4], bf[4];
        #pragma unroll
        for (int i = 0; i < 4; i++) {
            af[i] = *(const bfrag*)(&As[cur][0] + offA[i]);
            bf[i] = *(const bfrag*)(&Bs[cur][0] + offB[i]);
        }
        #pragma unroll
        for (int mt = 0; mt < 4; mt++)
            #pragma unroll
            for (int nt = 0; nt < 4; nt++)
                acc[mt * 4 + nt] = __builtin_amdgcn_mfma_f32_16x16x32_bf16(
                    af[mt], bf[nt], acc[mt * 4 + nt], 0, 0, 0);
        __builtin_amdgcn_s_barrier();
        cur = (cur == 2) ? 0 : cur + 1;
    }
    #undef STAGEW

    #pragma unroll
    for (int mt = 0; mt < 4; mt++)
        #pragma unroll
        for (int nt = 0; nt < 4; nt++) {
            ffrag v = acc[mt * 4 + nt];
            int col = n0 + wn * 64 + nt * 16 + fr;
            int row0 = m0 + wm * 64 + mt * 16 + q * 4;
            #pragma unroll
            for (int j = 0; j < 4; j++) {
                int m = row0 + j;
                if (m < cnt)
                    atomicAdd(&out[(long)idx[m] * N + col], gval[m] * v[j]);
            }
        }
}

__global__ __launch_bounds__(256) void moe_zero(int* __restrict__ idx, int* __restrict__ cnt)
{
    int i = blockIdx.x * 256 + threadIdx.x;
    if (i < NE * NTOK) idx[i] = 0;
    if (i < NE) cnt[i] = 0;
}

__global__ __launch_bounds__(256) void moe_build(
    const float* __restrict__ gates, int* __restrict__ idx,
    float* __restrict__ gval, int* __restrict__ cnt)
{
    int t = blockIdx.x * 256 + threadIdx.x;
    #pragma unroll
    for (int e = 0; e < NE; e++) {
        float g = gates[(long)t * NE + e];
        if (g > 0.f) {
            int ppos = atomicAdd(&cnt[e], 1);
            idx[e * NTOK + ppos] = t;
            gval[e * NTOK + ppos] = g;
        }
    }
}

__global__ __launch_bounds__(64) void moe_off(
    const int* __restrict__ cnt, int* __restrict__ off)
{
    if (threadIdx.x == 0) {
        int o = 0;
        for (int e = 0; e < NE; e++) { off[e] = o; o += (cnt[e] + 127) & ~127; }
    }
}

// ---------------------------------------------------------------------------
// Weight convert+transpose kernels (z-batched: src/dst strides per z)
// ---------------------------------------------------------------------------
__global__ __launch_bounds__(256) void convT_kernel(
    const float* __restrict__ src, u16* __restrict__ dst, int K, int N,
    long sS, long sD)
{
    __shared__ float t[32][33];
    src += (long)blockIdx.z * sS;
    dst += (long)blockIdx.z * sD;
    int n0 = blockIdx.x * 32, k0 = blockIdx.y * 32;
    int tx = threadIdx.x & 31, ty = threadIdx.x >> 5;
    #pragma unroll
    for (int j = 0; j < 4; j++)
        t[ty + j * 8][tx] = src[(long)(k0 + ty + j * 8) * N + n0 + tx];
    __syncthreads();
    #pragma unroll
    for (int j = 0; j < 4; j++)
        dst[(long)(n0 + ty + j * 8) * K + k0 + tx] = f2bf(t[tx][ty + j * 8]);
}

__global__ __launch_bounds__(256) void convT2_kernel(
    const float* __restrict__ src, u16* __restrict__ dhi, u16* __restrict__ dlo,
    int K, int N)
{
    __shared__ float t[32][33];
    int n0 = blockIdx.x * 32, k0 = blockIdx.y * 32;
    int tx = threadIdx.x & 31, ty = threadIdx.x >> 5;
    #pragma unroll
    for (int j = 0; j < 4; j++)
        t[ty + j * 8][tx] = src[(long)(k0 + ty + j * 8) * N + n0 + tx];
    __syncthreads();
    #pragma unroll
    for (int j = 0; j < 4; j++) {
        float v = t[tx][ty + j * 8];
        u16 hi, lo; split_bf(v, hi, lo);
        long o = (long)(n0 + ty + j * 8) * K + k0 + tx;
        dhi[o] = hi; dlo[o] = lo;
    }
}

__global__ __launch_bounds__(256) void conv_kernel(
    const float* __restrict__ s, u16* __restrict__ d)
{
    int i = (blockIdx.x * 256 + threadIdx.x) * 4;
    float4 v = *(const float4*)(s + i);
    ushort4 o;
    o.x = f2bf(v.x); o.y = f2bf(v.y); o.z = f2bf(v.z); o.w = f2bf(v.w);
    *(ushort4*)(d + i) = o;
}

// ---------------------------------------------------------------------------
// LayerNorm -> bf16 hi/lo
// ---------------------------------------------------------------------------
__global__ __launch_bounds__(256) void ln_kernel(
    const float* __restrict__ x, const float* __restrict__ g,
    const float* __restrict__ b, u16* __restrict__ hhi, u16* __restrict__ hlo)
{
    int token = blockIdx.x;
    int tid = threadIdx.x;
    const float* xr = x + (long)token * DD;
    float4 xv = *(const float4*)(xr + tid * 4);
    float s  = xv.x + xv.y + xv.z + xv.w;
    float sq = xv.x*xv.x + xv.y*xv.y + xv.z*xv.z + xv.w*xv.w;
    #pragma unroll
    for (int off = 32; off; off >>= 1) {
        s  += __shfl_xor(s, off);
        sq += __shfl_xor(sq, off);
    }
    __shared__ float ws[4], wq[4];
    int wid = tid >> 6, lane = tid & 63;
    if (lane == 0) { ws[wid] = s; wq[wid] = sq; }
    __syncthreads();
    s  = ws[0] + ws[1] + ws[2] + ws[3];
    sq = wq[0] + wq[1] + wq[2] + wq[3];
    float mu  = s * (1.f / DD);
    float var = sq * (1.f / DD) - mu * mu;
    float inv = rsqrtf(var + 1e-5f);
    float4 gv = *(const float4*)(g + tid * 4);
    float4 bv = *(const float4*)(b + tid * 4);
    float o[4];
    o[0] = (xv.x - mu) * inv * gv.x + bv.x;
    o[1] = (xv.y - mu) * inv * gv.y + bv.y;
    o[2] = (xv.z - mu) * inv * gv.z + bv.z;
    o[3] = (xv.w - mu) * inv * gv.w + bv.w;
    ushort4 oh, ol;
    split_bf(o[0], oh.x, ol.x); split_bf(o[1], oh.y, ol.y);
    split_bf(o[2], oh.z, ol.z); split_bf(o[3], oh.w, ol.w);
    *(ushort4*)(hhi + (long)token * DD + tid * 4) = oh;
    *(ushort4*)(hlo + (long)token * DD + tid * 4) = ol;
}

// ---------------------------------------------------------------------------
// SSM scan, 3-pass chunked
// ---------------------------------------------------------------------------
__global__ __launch_bounds__(256) void scan_p1(
    const float* __restrict__ u, const float* __restrict__ ssma,
    float* __restrict__ part)
{
    int i = blockIdx.x * 256 + threadIdx.x;
    int c = i & 2047, ch = (i >> 11) & 7, b = i >> 14;
    float a = 1.f / (1.f + expf(-ssma[c])), om = 1.f - a;
    const float* ux = u + (long)b * SS * (2 * DI) + DI + c;
    float h = 0.f;
    int t0 = ch * 128;
    #pragma unroll 4
    for (int t = t0; t < t0 + 128; ++t) h = a * h + om * ux[(long)t * (2 * DI)];
    part[i] = h;
}

__global__ __launch_bounds__(256) void scan_p2(
    const float* __restrict__ ssma, const float* __restrict__ part,
    float* __restrict__ init)
{
    int j = blockIdx.x * 256 + threadIdx.x;
    int c = j & 2047, b = j >> 11;
    float a = 1.f / (1.f + expf(-ssma[c]));
    float ap = a;
    #pragma unroll
    for (int i = 0; i < 7; i++) ap *= ap;
    float carry = 0.f;
    int base = b * 16384 + c;
    #pragma unroll
    for (int ch = 0; ch < 8; ch++) {
        init[base + ch * 2048] = carry;
        carry = ap * carry + part[base + ch * 2048];
    }
}

__global__ __launch_bounds__(256) void scan_p3(
    const float* __restrict__ u, const float* __restrict__ ssma,
    const float* __restrict__ init,
    u16* __restrict__ ihi, u16* __restrict__ ilo)
{
    int i = blockIdx.x * 256 + threadIdx.x;
    int c = i & 2047, ch = (i >> 11) & 7, b = i >> 14;
    float a = 1.f / (1.f + expf(-ssma[c])), om = 1.f - a;
    const float* uz = u + (long)b * SS * (2 * DI) + c;
    long obase = (long)b * SS * DI + c;
    float h = init[i];
    int t0 = ch * 128;
    #pragma unroll 2
    for (int t = t0; t < t0 + 128; ++t) {
        float z  = uz[(long)t * (2 * DI)];
        float xv = uz[(long)t * (2 * DI) + DI];
        h = a * h + om * xv;
        float sz = z / (1.f + expf(-z));
        u16 hi, lo; split_bf(h * sz, hi, lo);
        ihi[obase + (long)t * DI] = hi;
        ilo[obase + (long)t * DI] = lo;
    }
}

// ---------------------------------------------------------------------------
// QKV prep: fp32 qkv -> Q/K hi/lo [bh][s][64], Vt hi/lo [bh][64][s]
// ---------------------------------------------------------------------------
__global__ __launch_bounds__(256) void qk_prep(
    const float* __restrict__ qkv,
    u16* __restrict__ Qhi, u16* __restrict__ Qlo,
    u16* __restrict__ Khi, u16* __restrict__ Klo)
{
    int tok = blockIdx.x * 4 + (threadIdx.x >> 6);
    int l = threadIdx.x & 63;
    int b = tok >> 10, s = tok & 1023;
    const float* src = qkv + (long)tok * 3072;
    #pragma unroll
    for (int h = 0; h < 16; h++) {
        long dst = ((long)(b * 16 + h) * 1024 + s) * 64 + l;
        u16 hi, lo;
        split_bf(src[h * 64 + l], hi, lo);
        Qhi[dst] = hi; Qlo[dst] = lo;
        split_bf(src[1024 + h * 64 + l], hi, lo);
        Khi[dst] = hi; Klo[dst] = lo;
    }
}

__global__ __launch_bounds__(256) void v_prep(
    const float* __restrict__ qkv, u16* __restrict__ Vthi, u16* __restrict__ Vtlo)
{
    __shared__ float t[64][65];
    int st = blockIdx.x, bh = blockIdx.y;
    int b = bh >> 4, h = bh & 15;
    int tid = threadIdx.x;
    #pragma unroll
    for (int i = 0; i < 16; i++) {
        int e = tid + i * 256;
        int sl = e >> 6, d = e & 63;
        t[sl][d] = qkv[((long)(b * 1024 + st * 64 + sl)) * 3072 + 2048 + h * 64 + d];
    }
    __syncthreads();
    #pragma unroll
    for (int i = 0; i < 16; i++) {
        int e = tid + i * 256;
        int d = e >> 6, sl = e & 63;
        float v = t[sl][d];
        u16 hi, lo; split_bf(v, hi, lo);
        long o = ((long)bh * 64 + d) * 1024 + st * 64 + sl;
        Vthi[o] = hi; Vtlo[o] = lo;
    }
}

// ---------------------------------------------------------------------------
// MFMA split-bf16 causal flash attention. 4 waves, q-tile 64, K-tiles of 64.
// T14 async-STAGE: prefetch kt+1 K/V to regs before compute, ds_write after.
// ---------------------------------------------------------------------------
__global__ __launch_bounds__(256) void flash_mfma(
    const u16* __restrict__ Qhi, const u16* __restrict__ Qlo,
    const u16* __restrict__ Khi, const u16* __restrict__ Klo,
    const u16* __restrict__ Vthi, const u16* __restrict__ Vtlo,
    u16* __restrict__ aohi, u16* __restrict__ aolo)
{
    __shared__ u16 Qh[4096], Ql[4096], Kh[4096], Kl[4096], Vh[4096], Vl[4096];
    __shared__ u16 Ph[4][1024], Pl[4][1024];
    const int qt = (SS / 64 - 1) - blockIdx.x, bh = blockIdx.y;
    const int tid = threadIdx.x, w = tid >> 6, l = tid & 63;
    const int q0 = qt * 64;
    const int lr = l >> 3, ps = l & 7;
    const int cg = l & 15, quad = l >> 4;

    // stage Q tile + first K/V tile (kt=0)
    #pragma unroll
    for (int cc = 0; cc < 2; cc++) {
        int c = 2 * w + cc;
        int r = c * 8 + lr;
        int pl = ps ^ (r & 7);
        long gq = ((long)bh * 1024 + q0 + r) * 64 + pl * 8;
        long gk = ((long)bh * 1024 + r) * 64 + pl * 8;
        long gv = ((long)bh * 64 + r) * 1024 + pl * 8;
        gload16(Qhi + gq, Qh + c * 512 + l * 8);
        gload16(Qlo + gq, Ql + c * 512 + l * 8);
        gload16(Khi + gk, Kh + c * 512 + l * 8);
        gload16(Klo + gk, Kl + c * 512 + l * 8);
        gload16(Vthi + gv, Vh + c * 512 + l * 8);
        gload16(Vtlo + gv, Vl + c * 512 + l * 8);
    }
    __syncthreads();

    const int qrow = w * 16 + cg;
    const int offQ0 = flds(qrow, quad), offQ1 = flds(qrow, 4 + quad);
    bfrag qh0 = *(const bfrag*)(Qh + offQ0);
    bfrag qh1 = *(const bfrag*)(Qh + offQ1);
    bfrag ql0 = *(const bfrag*)(Ql + offQ0);
    bfrag ql1 = *(const bfrag*)(Ql + offQ1);

    ffrag O[4];
    #pragma unroll
    for (int i = 0; i < 4; i++) O[i] = (ffrag){0.f, 0.f, 0.f, 0.f};
    float mrun[4], lrun[4];
    #pragma unroll
    for (int j = 0; j < 4; j++) { mrun[j] = -1e30f; lrun[j] = 0.f; }

    for (int kt = 0; kt <= qt; kt++) {
        const bool pf = (kt < qt);
        // issue next tile's loads into registers (latency hides under compute)
        uint4 rkh[2], rkl[2], rvh[2], rvl[2];
        if (pf) {
            int k0n = (kt + 1) * 64;
            #pragma unroll
            for (int cc = 0; cc < 2; cc++) {
                int c = 2 * w + cc;
                int r = c * 8 + lr;
                int pl = ps ^ (r & 7);
                long gk = ((long)bh * 1024 + k0n + r) * 64 + pl * 8;
                long gv = ((long)bh * 64 + r) * 1024 + k0n + pl * 8;
                rkh[cc] = *(const uint4*)(Khi + gk);
                rkl[cc] = *(const uint4*)(Klo + gk);
                rvh[cc] = *(const uint4*)(Vthi + gv);
                rvl[cc] = *(const uint4*)(Vtlo + gv);
            }
        }

        float s[4][4];
        #pragma unroll
        for (int nt = 0; nt < 4; nt++) {
            ffrag sc = (ffrag){0.f, 0.f, 0.f, 0.f};
            int kr = nt * 16 + cg;
            bfrag kh0 = *(const bfrag*)(Kh + flds(kr, quad));
            bfrag kh1 = *(const bfrag*)(Kh + flds(kr, 4 + quad));
            bfrag kl0 = *(const bfrag*)(Kl + flds(kr, quad));
            bfrag kl1 = *(const bfrag*)(Kl + flds(kr, 4 + quad));
            sc = __builtin_amdgcn_mfma_f32_16x16x32_bf16(qh0, kh0, sc, 0, 0, 0);
            sc = __builtin_amdgcn_mfma_f32_16x16x32_bf16(qh1, kh1, sc, 0, 0, 0);
            sc = __builtin_amdgcn_mfma_f32_16x16x32_bf16(qh0, kl0, sc, 0, 0, 0);
            sc = __builtin_amdgcn_mfma_f32_16x16x32_bf16(qh1, kl1, sc, 0, 0, 0);
            sc = __builtin_amdgcn_mfma_f32_16x16x32_bf16(ql0, kh0, sc, 0, 0, 0);
            sc = __builtin_amdgcn_mfma_f32_16x16x32_bf16(ql1, kh1, sc, 0, 0, 0);
            bool last = (kt == qt);
            #pragma unroll
            for (int j = 0; j < 4; j++) {
                float v = sc[j] * 0.125f;
                if (last && (nt * 16 + cg > w * 16 + quad * 4 + j)) v = -1e30f;
                s[nt][j] = v;
            }
        }
        #pragma unroll
        for (int j = 0; j < 4; j++) {
            float rm = fmaxf(fmaxf(s[0][j], s[1][j]), fmaxf(s[2][j], s[3][j]));
            rm = fmaxf(rm, __shfl_xor(rm, 1));
            rm = fmaxf(rm, __shfl_xor(rm, 2));
            rm = fmaxf(rm, __shfl_xor(rm, 4));
            rm = fmaxf(rm, __shfl_xor(rm, 8));
            float mn = fmaxf(mrun[j], rm);
            float alpha = __expf(mrun[j] - mn);
            float rs = 0.f;
            #pragma unroll
            for (int nt = 0; nt < 4; nt++) {
                float pv = __expf(s[nt][j] - mn);
                s[nt][j] = pv;
                rs += pv;
            }
            rs += __shfl_xor(rs, 1);
            rs += __shfl_xor(rs, 2);
            rs += __shfl_xor(rs, 4);
            rs += __shfl_xor(rs, 8);
            lrun[j] = lrun[j] * alpha + rs;
            mrun[j] = mn;
            #pragma unroll
            for (int ct = 0; ct < 4; ct++) O[ct][j] *= alpha;
        }
        // P (C-layout) -> per-wave LDS, split hi/lo, swizzled for A-frag reads
        #pragma unroll
        for (int nt = 0; nt < 4; nt++)
            #pragma unroll
            for (int j = 0; j < 4; j++) {
                int row = quad * 4 + j, col = nt * 16 + cg;
                int addr = row * 64 + (((col >> 3) ^ (row & 7)) << 3) + (col & 7);
                float pv = s[nt][j];
                u16 phv = f2bf(pv);
                float pf2 = __uint_as_float((unsigned)phv << 16);
                Ph[w][addr] = phv;
                Pl[w][addr] = f2bf(pv - pf2);
            }
        bfrag p0h = *(const bfrag*)(&Ph[w][0] + flds(cg, quad));
        bfrag p1h = *(const bfrag*)(&Ph[w][0] + flds(cg, 4 + quad));
        bfrag p0l = *(const bfrag*)(&Pl[w][0] + flds(cg, quad));
        bfrag p1l = *(const bfrag*)(&Pl[w][0] + flds(cg, 4 + quad));
        #pragma unroll
        for (int ct = 0; ct < 4; ct++) {
            int vr = ct * 16 + cg;
            bfrag vh0 = *(const bfrag*)(Vh + flds(vr, quad));
            bfrag vh1 = *(const bfrag*)(Vh + flds(vr, 4 + quad));
            bfrag vl0 = *(const bfrag*)(Vl + flds(vr, quad));
            bfrag vl1 = *(const bfrag*)(Vl + flds(vr, 4 + quad));
            O[ct] = __builtin_amdgcn_mfma_f32_16x16x32_bf16(p0h, vh0, O[ct], 0, 0, 0);
            O[ct] = __builtin_amdgcn_mfma_f32_16x16x32_bf16(p1h, vh1, O[ct], 0, 0, 0);
            O[ct] = __builtin_amdgcn_mfma_f32_16x16x32_bf16(p0h, vl0, O[ct], 0, 0, 0);
            O[ct] = __builtin_amdgcn_mfma_f32_16x16x32_bf16(p1h, vl1, O[ct], 0, 0, 0);
            O[ct] = __builtin_amdgcn_mfma_f32_16x16x32_bf16(p0l, vh0, O[ct], 0, 0, 0);
            O[ct] = __builtin_amdgcn_mfma_f32_16x16x32_bf16(p1l, vh1, O[ct], 0, 0, 0);
        }
        // write prefetched tile into LDS for next iteration
        if (pf) {
            __syncthreads();
            #pragma unroll
            for (int cc = 0; cc < 2; cc++) {
                int c = 2 * w + cc;
                *(uint4*)(Kh + c * 512 + l * 8) = rkh[cc];
                *(uint4*)(Kl + c * 512 + l * 8) = rkl[cc];
                *(uint4*)(Vh + c * 512 + l * 8) = rvh[cc];
                *(uint4*)(Vl + c * 512 + l * 8) = rvl[cc];
            }
            __syncthreads();
        }
    }
    int b = bh >> 4, h = bh & 15;
    #pragma unroll
    for (int j = 0; j < 4; j++) {
        float inv = 1.f / lrun[j];
        int srow = q0 + w * 16 + quad * 4 + j;
        long base = ((long)(b * 1024 + srow)) * 1024 + h * 64 + cg;
        #pragma unroll
        for (int ct = 0; ct < 4; ct++) {
            float v = O[ct][j] * inv;
            u16 hi, lo; split_bf(v, hi, lo);
            aohi[base + ct * 16] = hi;
            aolo[base + ct * 16] = lo;
        }
    }
}

// ---------------------------------------------------------------------------
// x1 combine, router, softmax512
// ---------------------------------------------------------------------------
__global__ __launch_bounds__(256) void combine_kernel(
    const float* __restrict__ x, const float* __restrict__ ssm,
    const float* __restrict__ attn, const float* __restrict__ bs,
    const float* __restrict__ ba, float* __restrict__ x1, u16* __restrict__ x1h)
{
    int i = (blockIdx.x * 256 + threadIdx.x) * 4;
    int d = i & (DD - 1);
    float4 xv = *(const float4*)(x + i);
    float4 sv = *(const float4*)(ssm + i);
    float4 av = *(const float4*)(attn + i);
    float4 b1 = *(const float4*)(bs + d);
    float4 b2 = *(const float4*)(ba + d);
    float4 o;
    o.x = xv.x + b1.x * sv.x + b2.x * av.x;
    o.y = xv.y + b1.y * sv.y + b2.y * av.y;
    o.z = xv.z + b1.z * sv.z + b2.z * av.z;
    o.w = xv.w + b1.w * sv.w + b2.w * av.w;
    *(float4*)(x1 + i) = o;
    ushort4 oh;
    oh.x = f2bf(o.x); oh.y = f2bf(o.y); oh.z = f2bf(o.z); oh.w = f2bf(o.w);
    *(ushort4*)(x1h + i) = oh;
}

__global__ __launch_bounds__(256) void router_kernel(
    const float* __restrict__ x1, const int* __restrict__ enc_avail,
    const float* __restrict__ rW, const float* __restrict__ rb,
    float* __restrict__ gates)
{
    int token = blockIdx.x * 4 + (threadIdx.x >> 6);
    int lane = threadIdx.x & 63;
    int b = token >> 10;
    float acc[NE];
    #pragma unroll
    for (int e = 0; e < NE; e++) acc[e] = 0.f;
    const float* xrow = x1 + (long)token * DD;
    for (int d = lane; d < DD; d += 64) {
        float xv = xrow[d];
        const float* w = rW + (long)d * NE;
        #pragma unroll
        for (int e = 0; e < NE; e++) acc[e] += xv * w[e];
    }
    #pragma unroll
    for (int e = 0; e < NE; e++) {
        #pragma unroll
        for (int off = 32; off; off >>= 1) acc[e] += __shfl_xor(acc[e], off);
    }
    if (lane == 0) {
        int avail = enc_avail[b];
        float av = (float)avail;
        float lg[NE], pr[NE];
        #pragma unroll
        for (int e = 0; e < NE; e++) lg[e] = acc[e] + av * rW[(long)DD * NE + e] + rb[e];
        float mx = lg[0];
        #pragma unroll
        for (int e = 1; e < NE; e++) mx = fmaxf(mx, lg[e]);
        float sum = 0.f;
        #pragma unroll
        for (int e = 0; e < NE; e++) { pr[e] = expf(lg[e] - mx); sum += pr[e]; }
        float isum = 1.f / sum;
        #pragma unroll
        for (int e = 0; e < NE; e++) pr[e] *= isum;
        int i1 = 0;
        #pragma unroll
        for (int e = 1; e < NE; e++) if (pr[e] > pr[i1]) i1 = e;
        int i2 = (i1 == 0) ? 1 : 0;
        #pragma unroll
        for (int e = 0; e < NE; e++) if (e != i1 && pr[e] > pr[i2]) i2 = e;
        float g[NE];
        #pragma unroll
        for (int e = 0; e < NE; e++) g[e] = 0.f;
        g[i1] = pr[i1]; g[i2] = pr[i2];
        float s1 = g[i1] + g[i2] + 1e-9f;
        #pragma unroll
        for (int e = 0; e < NE; e++) g[e] /= s1;
        if (avail == 0) { g[0] = 0.f; g[1] = 0.f; }
        float s2 = 1e-6f;
        #pragma unroll
        for (int e = 0; e < NE; e++) s2 += g[e];
        float is2 = 1.f / s2;
        #pragma unroll
        for (int e = 0; e < NE; e++) gates[(long)token * NE + e] = g[e] * is2;
    }
}

__global__ __launch_bounds__(256) void softmax512_kernel(
    const float* __restrict__ sA, u16* __restrict__ pA, float scale)
{
    int row = blockIdx.x * 4 + (threadIdx.x >> 6);
    int lane = threadIdx.x & 63;
    const float* r = sA + (long)row * ENCS;
    u16* o = pA + (long)row * ENCS;
    float v[8];
    #pragma unroll
    for (int j = 0; j < 8; j++) v[j] = r[lane + j * 64] * scale;
    float mx = v[0];
    #pragma unroll
    for (int j = 1; j < 8; j++) mx = fmaxf(mx, v[j]);
    #pragma unroll
    for (int off = 32; off; off >>= 1) mx = fmaxf(mx, __shfl_xor(mx, off));
    float sum = 0.f;
    #pragma unroll
    for (int j = 0; j < 8; j++) { v[j] = __expf(v[j] - mx); sum += v[j]; }
    #pragma unroll
    for (int off = 32; off; off >>= 1) sum += __shfl_xor(sum, off);
    float inv = 1.f / sum;
    #pragma unroll
    for (int j = 0; j < 8; j++) o[lane + j * 64] = f2bf(v[j] * inv);
}

// ---------------------------------------------------------------------------
// launch
// ---------------------------------------------------------------------------
extern "C" void kernel_launch(void* const* d_in, const int* in_sizes, int n_in,
                              void* d_out, int out_size, void* d_ws, size_t ws_size,
                              hipStream_t stream) {
    const float* x    = (const float*)d_in[0];
    const float* enc  = (const float*)d_in[1];
    const int*   eav  = (const int*)d_in[4];
    const float* ln_g = (const float*)d_in[5];
    const float* ln_b = (const float*)d_in[6];
    const float* Win  = (const float*)d_in[7];
    const float* ssma = (const float*)d_in[8];
    const float* Wout = (const float*)d_in[9];
    const float* Wqkv = (const float*)d_in[10];
    const float* Wo   = (const float*)d_in[11];
    const float* bSsm = (const float*)d_in[12];
    const float* bAtt = (const float*)d_in[13];
    const float* seW1 = (const float*)d_in[14];
    const float* seb1 = (const float*)d_in[15];
    const float* seW2 = (const float*)d_in[16];
    const float* seb2 = (const float*)d_in[17];
    const float* rW   = (const float*)d_in[18];
    const float* rb   = (const float*)d_in[19];
    const float* eaWq = (const float*)d_in[20];
    const float* eaWk = (const float*)d_in[21];
    const float* eaWv = (const float*)d_in[22];
    const float* eaWo = (const float*)d_in[23];
    const float* eaW1 = (const float*)d_in[24];
    const float* eaW2 = (const float*)d_in[25];
    const float* ebW1 = (const float*)d_in[26];
    const float* ebW2 = (const float*)d_in[27];
    float* out = (float*)d_out;

    // ---- workspace layout (~185.5 MB) ----
    float* F = (float*)d_ws;
    float* f_big  = F;                    // 16,777,216 fl (64MB)
    float* f_ssm  = F + 16777216;         // 4,194,304
    float* f_x1   = F + 20971520;         // 4,194,304 (persists)
    float* f_part = F + 25165824;         // 65,536
    float* f_init = F + 25231360;         // 65,536
    float* f_gate = F + 25296896;         // 32,768
    u16* U = (u16*)(F + 25329664);
    u16* u_h_hi  = U;                     // 4,194,304
    u16* u_h_lo  = U + 4194304;           // 4,194,304 (x1 bf16, persists)
    u16* u_in_hi = U + 8388608;           // 8,388,608
    u16* u_in_lo = U + 16777216;          // 8,388,608
    u16* u_ao_hi = U + 25165824;          // 4,194,304
    u16* u_ao_lo = U + 29360128;          // 4,194,304
    u16* u_wt    = U + 33554432;          // 4,194,304
    u16* u_wt_lo = U + 37748736;          // 4,194,304
    int*   moe_idx = (int*)(U + 41943040);        // 8*4096 ints
    float* moe_gv  = (float*)(moe_idx + NE * NTOK);
    int*   moe_cnt = (int*)(moe_gv + NE * NTOK);  // 8 ints
    int*   moe_offp = moe_cnt + NE;               // 8 ints

    // main-phase aliases
    float* f_u    = f_big;
    float* f_qkv  = f_big;
    float* f_attn = f_big + 12582912;
    u16*   u_ff   = (u16*)f_big;          // shared-FFN intermediate (16MB)
    u16*   u_enc  = u_h_hi + 2097152;     // encoder bf16 (4MB, persists in expert phase)
    u16*   u_x1   = u_h_lo;
    // flash staging buffers
    u16* u_Qhi = u_h_hi, *u_Qlo = u_h_lo;
    u16* u_Khi = u_in_hi, *u_Klo = u_in_hi + 4194304;
    u16* u_Vthi = u_in_lo, *u_Vtlo = u_in_lo + 4194304;

    // expert-phase buffers (all exact-fit, see liveness notes)
    u16*   wq2   = u_wt;                              // 2 x DD*DD
    u16*   wk2   = u_wt_lo;
    u16*   wv2   = (u16*)f_ssm;
    u16*   wo2   = (u16*)f_ssm + 4194304;
    u16*   qA2   = u_ao_hi;                           // 2 x NTOK*DD (spans ao_hi+ao_lo)
    u16*   kA2   = u_in_hi;                           // 2 x 2048*DD
    u16*   vAt2  = u_in_hi + 4194304;                 // 2 x 4 x DD*ENCS
    float* sA2   = (float*)u_in_lo;                   // 8 x SS*ENCS fp32
    u16*   ctx2  = u_in_lo;                           // 8 x SS*DD (after sA2 dead)
    u16*   ffpool = (u16*)f_big;                      // 10240 x DFE rows (40MB)
    u16*   hA2   = (u16*)(f_big + 10485760);          // 2 x NTOK*DD (16MB)
    u16*   pA2   = (u16*)(f_big + 14680064);          // 8 x SS*ENCS bf16 (8MB)
    u16*   w1a   = u_ao_hi;                           // experts 0-3 W1 (after qA2 dead)
    u16*   w1b   = u_in_hi;                           // experts 4-7 W1 (after kA2/vAt2 dead)
    u16*   w2a   = u_wt;                              // experts 0-3 W2 (after wq2/wk2 dead)
    u16*   w2b   = (u16*)f_ssm;                       // experts 4-7 W2 (after wv2/wo2 dead)

    #define CONVT(src, Kd, Nd)  convT_kernel <<<dim3((Nd)/32,(Kd)/32,1), dim3(256), 0, stream>>>(src, u_wt, Kd, Nd, 0, 0)
    #define CONVTB(src, dst, Kd, Nd, nb) convT_kernel<<<dim3((Nd)/32,(Kd)/32,(nb)), dim3(256), 0, stream>>>(src, dst, Kd, Nd, (long)(Kd)*(Nd), (long)(Kd)*(Nd))
    #define CONVT2(src, Kd, Nd) convT2_kernel<<<dim3((Nd)/32,(Kd)/32), dim3(256), 0, stream>>>(src, u_wt, u_wt_lo, Kd, Nd)

    // 1) h = LN(x) (bf16 hi/lo)
    ln_kernel<<<dim3(NTOK), dim3(256), 0, stream>>>(x, ln_g, ln_b, u_h_hi, u_h_lo);
    // 2) u = h @ Win (fused split 3-product GEMM)
    CONVT2(Win, DD, 2 * DI);
    ggemm3(stream, u_h_hi, u_h_lo, u_wt, u_wt_lo, f_u, NTOK, 2 * DI, DD);
    // 3) chunked scan -> inner (bf16 hi/lo)
    scan_p1<<<dim3(256), dim3(256), 0, stream>>>(f_u, ssma, f_part);
    scan_p2<<<dim3(32), dim3(256), 0, stream>>>(ssma, f_part, f_init);
    scan_p3<<<dim3(256), dim3(256), 0, stream>>>(f_u, ssma, f_init, u_in_hi, u_in_lo);
    // 4) ssm_out = inner @ Wout (fused split)
    CONVT2(Wout, DI, DD);
    ggemm3(stream, u_in_hi, u_in_lo, u_wt, u_wt_lo, f_ssm, NTOK, DD, DI);
    // 5) qkv = h @ Wqkv (fused split; overwrites u region)
    CONVT2(Wqkv, DD, 3 * DD);
    ggemm3(stream, u_h_hi, u_h_lo, u_wt, u_wt_lo, f_qkv, NTOK, 3 * DD, DD);
    // 5.5) split qkv into per-head hi/lo layouts
    qk_prep<<<dim3(NTOK / 4), dim3(256), 0, stream>>>(f_qkv, u_Qhi, u_Qlo, u_Khi, u_Klo);
    v_prep<<<dim3(SS / 64, BB * NH), dim3(256), 0, stream>>>(f_qkv, u_Vthi, u_Vtlo);
    // 6) MFMA flash attention -> ao hi/lo
    flash_mfma<<<dim3(SS / 64, BB * NH), dim3(256), 0, stream>>>(
        u_Qhi, u_Qlo, u_Khi, u_Klo, u_Vthi, u_Vtlo, u_ao_hi, u_ao_lo);
    // 7) attn = ao @ Wo (fused split)
    CONVT2(Wo, DD, DD);
    ggemm3(stream, u_ao_hi, u_ao_lo, u_wt, u_wt_lo, f_attn, NTOK, DD, DD);
    // 8) x1 = x + bs*ssm + ba*attn
    combine_kernel<<<dim3(NTOK * DD / 1024), dim3(256), 0, stream>>>(
        x, f_ssm, f_attn, bSsm, bAtt, f_x1, u_x1);
    // 9) router + expert token lists + prefix offsets
    router_kernel<<<dim3(NTOK / 4), dim3(256), 0, stream>>>(f_x1, eav, rW, rb, f_gate);
    moe_zero<<<dim3((NE * NTOK + 255) / 256), dim3(256), 0, stream>>>(moe_idx, moe_cnt);
    moe_build<<<dim3(NTOK / 256), dim3(256), 0, stream>>>(f_gate, moe_idx, moe_gv, moe_cnt);
    moe_off<<<dim3(1), dim3(64), 0, stream>>>(moe_cnt, moe_offp);
    // 10) ff = gelu(x1 @ seW1 + b1) (bf16)
    CONVT(seW1, DD, DFF);
    ggemm(stream, u_x1, u_wt, nullptr, u_ff, NTOK, DFF, DD, 1, 0, 0, 0,
          seb1, nullptr, nullptr, 0, 0, 1);
    // 11) out = x1 + ff @ seW2 + b2 (fp32)
    CONVT(seW2, DFF, DD);
    ggemm(stream, u_ff, u_wt, out, nullptr, NTOK, DD, DFF, 1, 0, 0, 0,
          seb2, f_x1, nullptr, 0, 0, 0);
    // 12) encoder -> bf16
    conv_kernel<<<dim3(BB * ENCS * DD / 1024), dim3(256), 0, stream>>>(enc, u_enc);

    // 13) type-A cross-attention, batched across both experts
    CONVTB(eaWq, wq2, DD, DD, 2);
    CONVTB(eaWk, wk2, DD, DD, 2);
    CONVTB(eaWv, wv2, DD, DD, 2);
    CONVTB(eaWo, wo2, DD, DD, 2);
    // qA[e] = x1 @ Wq[e]   (batch 2)
    ggemm(stream, u_x1, wq2, nullptr, qA2, NTOK, DD, DD, 2,
          0, (long)DD * DD, (long)NTOK * DD, nullptr, nullptr, nullptr, 0, 0, 0);
    // kA[e] = enc @ Wk[e]  (batch 2)
    ggemm(stream, u_enc, wk2, nullptr, kA2, BB * ENCS, DD, DD, 2,
          0, (long)DD * DD, (long)BB * ENCS * DD, nullptr, nullptr, nullptr, 0, 0, 0);
    // vAt[e][b] = (enc[b] @ Wv[e])^T  (2 launches, batch 4 each)
    for (int e = 0; e < NA; ++e)
        ggemm(stream, wv2 + (long)e * DD * DD, u_enc, nullptr,
              vAt2 + (long)e * 4 * DD * ENCS, DD, ENCS, DD, BB,
              0, (long)ENCS * DD, (long)DD * ENCS, nullptr, nullptr, nullptr, 0, 0, 0);
    // sA = qA @ kA^T  (batch 8 = [e][b])
    ggemm(stream, qA2, kA2, sA2, nullptr, SS, ENCS, DD, 2 * BB,
          (long)SS * DD, (long)ENCS * DD, (long)SS * ENCS,
          nullptr, nullptr, nullptr, 0, 0, 0);
    softmax512_kernel<<<dim3(2 * NTOK / 4), dim3(256), 0, stream>>>(sA2, pA2, 0.03125f);
    // ctx = pA @ vAt^T  (batch 8)
    ggemm(stream, pA2, vAt2, nullptr, ctx2, SS, DD, ENCS, 2 * BB,
          (long)SS * ENCS, (long)DD * ENCS, (long)SS * DD,
          nullptr, nullptr, nullptr, 0, 0, 0);
    // hA[e] = x1 + ctx[e] @ Wo[e]  (batch 2)
    ggemm(stream, ctx2, wo2, nullptr, hA2, NTOK, DD, DD, 2,
          (long)NTOK * DD, (long)DD * DD, (long)NTOK * DD,
          nullptr, f_x1, nullptr, 0, 0, 0);

    // 14) all-expert sparse FFN, fully batched
    CONVTB(eaW1, w1a, DD, DFE, 2);                       // experts 0,1
    CONVTB(ebW1, w1a + 2 * W1SZ, DD, DFE, 2);            // experts 2,3
    CONVTB(ebW1 + 2 * W1SZ, w1b, DD, DFE, 4);            // experts 4-7
    CONVTB(eaW2, w2a, DFE, DD, 2);
    CONVTB(ebW2, w2a + 2 * W1SZ, DFE, DD, 2);
    CONVTB(ebW2 + 2 * W1SZ, w2b, DFE, DD, 4);
    moe_w1<<<dim3(DFE / 128, NTOK / 128, NE), dim3(256), 0, stream>>>(
        hA2, u_x1, w1a, w1b, ffpool, moe_idx, moe_cnt, moe_offp, DFE, DD);
    moe_w2<<<dim3(DD / 128, NTOK / 128, NE), dim3(256), 0, stream>>>(
        ffpool, w2a, w2b, out, moe_idx, moe_gv, moe_cnt, moe_offp, DD, DFE);
    (void)in_sizes; (void)n_in; (void)out_size; (void)ws_size;
}

// Round 4
// 1423.754 us; speedup vs baseline: 1.0375x; 1.0375x over previous
//
#include <hip/hip_runtime.h>
#include <hip/hip_bf16.h>
#include <math.h>

// Problem constants
#define BB 4
#define SS 1024
#define DD 1024
#define ENCS 512
#define DI 2048
#define DFF 4096
#define DFE 2048
#define NA 2
#define NB 6
#define NE 8
#define NH 16
#define NTOK (BB*SS)   // 4096
#define W1SZ ((long)DD*DFE)   // elems per expert W1 (= W2)

typedef unsigned short u16;
typedef __bf16 bfrag __attribute__((ext_vector_type(8)));
typedef float  ffrag __attribute__((ext_vector_type(4)));

// ---------------------------------------------------------------------------
// helpers
// ---------------------------------------------------------------------------
__device__ __forceinline__ float gelu_f(float x) {
    const float c = 0.7978845608028654f;
    float t = tanhf(c * (x + 0.044715f * x * x * x));
    return 0.5f * x * (1.f + t);
}

__device__ __forceinline__ u16 f2bf(float f) {
    unsigned u = __float_as_uint(f);
    u += 0x7fffu + ((u >> 16) & 1u);   // RNE
    return (u16)(u >> 16);
}

__device__ __forceinline__ void split_bf(float v, u16& hi, u16& lo) {
    hi = f2bf(v);
    float hf = __uint_as_float((unsigned)hi << 16);
    lo = f2bf(v - hf);
}

typedef const __attribute__((address_space(1))) unsigned int* gas_t;
typedef __attribute__((address_space(3))) unsigned int* las_t;
__device__ __forceinline__ void gload16(const u16* g, u16* l) {
    __builtin_amdgcn_global_load_lds((gas_t)g, (las_t)l, 16, 0, 0);
}

// LDS fragment address in a 64-col bf16 tile with 16B-block XOR swizzle
__device__ __forceinline__ int flds(int row, int p) {
    return row * 64 + (((p ^ (row & 7)) & 7) << 3);
}

// ---------------------------------------------------------------------------
// MFMA bf16 GEMM: C[M,N] = A[M,K] @ Bt[N,K]^T (128x128 tile, BK=32)
// Depth-3 prefetch ring: 3 LDS buffers, counted vmcnt(8/4/0), raw barriers.
// ---------------------------------------------------------------------------
__global__ __launch_bounds__(256) void gemm_mfma(
    const u16* __restrict__ A, const u16* __restrict__ Bt,
    float* __restrict__ Cf, u16* __restrict__ Ch,
    int M, int N, int K,
    long sAb, long sBb, long sCb,
    const float* __restrict__ bias, const float* __restrict__ res,
    const float* __restrict__ rowscale, int rs_stride,
    int accum, int do_gelu)
{
    __shared__ u16 As[3][4096];
    __shared__ u16 Bs[3][4096];
    const int tid = threadIdx.x;
    const int w = tid >> 6, l = tid & 63;
    const int wm = w >> 1, wn = w & 1;
    const int bz = blockIdx.z;
    A  += (long)bz * sAb;
    Bt += (long)bz * sBb;
    const int m0 = blockIdx.y * 128, n0 = blockIdx.x * 128;

    const int c0 = 2 * w, c1 = c0 + 1;
    const int rl0 = c0 * 16 + (l >> 2), rl1 = c1 * 16 + (l >> 2);
    const int p = l & 3;
    const int gb0 = p ^ ((rl0 ^ (rl0 >> 2)) & 3);
    const int gb1 = p ^ ((rl1 ^ (rl1 >> 2)) & 3);
    const u16* gA0 = A  + (long)(m0 + rl0) * K + gb0 * 8;
    const u16* gA1 = A  + (long)(m0 + rl1) * K + gb1 * 8;
    const u16* gB0 = Bt + (long)(n0 + rl0) * K + gb0 * 8;
    const u16* gB1 = Bt + (long)(n0 + rl1) * K + gb1 * 8;
    const int d0 = c0 * 512, d1 = c1 * 512;

    const int q = l >> 4, fr = l & 15;
    int offA[4], offB[4];
    #pragma unroll
    for (int t = 0; t < 4; t++) {
        int ra = wm * 64 + t * 16 + fr;
        offA[t] = ra * 32 + (q ^ ((ra ^ (ra >> 2)) & 3)) * 8;
        int rb = wn * 64 + t * 16 + fr;
        offB[t] = rb * 32 + (q ^ ((rb ^ (rb >> 2)) & 3)) * 8;
    }

    ffrag acc[16];
    #pragma unroll
    for (int i = 0; i < 16; i++) acc[i] = (ffrag){0.f, 0.f, 0.f, 0.f};

    const int nsteps = K >> 5;
    #define STAGE1(bi, k0) do { \
        gload16(gA0 + (k0), &As[bi][d0]); \
        gload16(gA1 + (k0), &As[bi][d1]); \
        gload16(gB0 + (k0), &Bs[bi][d0]); \
        gload16(gB1 + (k0), &Bs[bi][d1]); } while (0)

    STAGE1(0, 0);
    STAGE1(1, 32);
    int cur = 0;
    for (int t = 0; t < nsteps; ++t) {
        int rem = nsteps - 1 - t;
        if (rem >= 2) {
            int nb = cur + 2; if (nb >= 3) nb -= 3;
            STAGE1(nb, (t + 2) << 5);
            asm volatile("s_waitcnt vmcnt(8)" ::: "memory");
        } else if (rem == 1) {
            asm volatile("s_waitcnt vmcnt(4)" ::: "memory");
        } else {
            asm volatile("s_waitcnt vmcnt(0)" ::: "memory");
        }
        __builtin_amdgcn_s_barrier();
        bfrag af[4], bf[4];
        #pragma unroll
        for (int i = 0; i < 4; i++) {
            af[i] = *(const bfrag*)(&As[cur][0] + offA[i]);
            bf[i] = *(const bfrag*)(&Bs[cur][0] + offB[i]);
        }
        #pragma unroll
        for (int mt = 0; mt < 4; mt++)
            #pragma unroll
            for (int nt = 0; nt < 4; nt++)
                acc[mt * 4 + nt] = __builtin_amdgcn_mfma_f32_16x16x32_bf16(
                    af[mt], bf[nt], acc[mt * 4 + nt], 0, 0, 0);
        __builtin_amdgcn_s_barrier();
        cur = (cur == 2) ? 0 : cur + 1;
    }
    #undef STAGE1

    const long cbase = (long)bz * sCb;
    #pragma unroll
    for (int mt = 0; mt < 4; mt++) {
        #pragma unroll
        for (int nt = 0; nt < 4; nt++) {
            ffrag v = acc[mt * 4 + nt];
            int col = n0 + wn * 64 + nt * 16 + fr;
            int row0 = m0 + wm * 64 + mt * 16 + q * 4;
            float bv = bias ? bias[col] : 0.f;
            #pragma unroll
            for (int j = 0; j < 4; j++) {
                int row = row0 + j;
                float x = v[j] + bv;
                if (do_gelu) x = gelu_f(x);
                if (rowscale) x *= rowscale[(long)row * rs_stride];
                long idx = cbase + (long)row * N + col;
                if (res) x += res[(long)row * N + col];
                if (accum) { Cf[idx] += x; }
                else {
                    if (Cf) Cf[idx] = x;
                    if (Ch) Ch[idx] = f2bf(x);
                }
            }
        }
    }
}

// ---------------------------------------------------------------------------
// Fused split-bf16 GEMM: C = Ahi@Bhi^T + Ahi@Blo^T + Alo@Bhi^T in ONE pass.
// Depth-2 (LDS-bound at 64KB); 48 MFMA per K-step amortizes latency.
// ---------------------------------------------------------------------------
__global__ __launch_bounds__(256) void gemm3_mfma(
    const u16* __restrict__ Ahi, const u16* __restrict__ Alo,
    const u16* __restrict__ Bhi, const u16* __restrict__ Blo,
    float* __restrict__ Cf, int M, int N, int K)
{
    __shared__ u16 Ah[2][4096];
    __shared__ u16 Al[2][4096];
    __shared__ u16 Bh[2][4096];
    __shared__ u16 Bl[2][4096];
    const int tid = threadIdx.x;
    const int w = tid >> 6, l = tid & 63;
    const int wm = w >> 1, wn = w & 1;
    const int m0 = blockIdx.y * 128, n0 = blockIdx.x * 128;

    const int c0 = 2 * w, c1 = c0 + 1;
    const int rl0 = c0 * 16 + (l >> 2), rl1 = c1 * 16 + (l >> 2);
    const int p = l & 3;
    const int gb0 = p ^ ((rl0 ^ (rl0 >> 2)) & 3);
    const int gb1 = p ^ ((rl1 ^ (rl1 >> 2)) & 3);
    const long oa0 = (long)(m0 + rl0) * K + gb0 * 8;
    const long oa1 = (long)(m0 + rl1) * K + gb1 * 8;
    const long ob0 = (long)(n0 + rl0) * K + gb0 * 8;
    const long ob1 = (long)(n0 + rl1) * K + gb1 * 8;
    const u16* gAh0 = Ahi + oa0; const u16* gAh1 = Ahi + oa1;
    const u16* gAl0 = Alo + oa0; const u16* gAl1 = Alo + oa1;
    const u16* gBh0 = Bhi + ob0; const u16* gBh1 = Bhi + ob1;
    const u16* gBl0 = Blo + ob0; const u16* gBl1 = Blo + ob1;
    const int d0 = c0 * 512, d1 = c1 * 512;

    const int q = l >> 4, fr = l & 15;
    int offA[4], offB[4];
    #pragma unroll
    for (int t = 0; t < 4; t++) {
        int ra = wm * 64 + t * 16 + fr;
        offA[t] = ra * 32 + (q ^ ((ra ^ (ra >> 2)) & 3)) * 8;
        int rb = wn * 64 + t * 16 + fr;
        offB[t] = rb * 32 + (q ^ ((rb ^ (rb >> 2)) & 3)) * 8;
    }

    ffrag acc[16];
    #pragma unroll
    for (int i = 0; i < 16; i++) acc[i] = (ffrag){0.f, 0.f, 0.f, 0.f};

    const int nsteps = K >> 5;
    #define STAGE3(bi, k0) do { \
        gload16(gAh0 + (k0), &Ah[bi][d0]); \
        gload16(gAh1 + (k0), &Ah[bi][d1]); \
        gload16(gAl0 + (k0), &Al[bi][d0]); \
        gload16(gAl1 + (k0), &Al[bi][d1]); \
        gload16(gBh0 + (k0), &Bh[bi][d0]); \
        gload16(gBh1 + (k0), &Bh[bi][d1]); \
        gload16(gBl0 + (k0), &Bl[bi][d0]); \
        gload16(gBl1 + (k0), &Bl[bi][d1]); } while (0)

    int cur = 0;
    STAGE3(0, 0);
    for (int t = 0; t < nsteps; ++t) {
        if (t + 1 < nsteps) {
            STAGE3(cur ^ 1, (t + 1) << 5);
            asm volatile("s_waitcnt vmcnt(8)" ::: "memory");
        } else {
            asm volatile("s_waitcnt vmcnt(0)" ::: "memory");
        }
        __builtin_amdgcn_s_barrier();
        bfrag ah[4], al[4], bh[4], bl[4];
        #pragma unroll
        for (int i = 0; i < 4; i++) {
            ah[i] = *(const bfrag*)(&Ah[cur][0] + offA[i]);
            al[i] = *(const bfrag*)(&Al[cur][0] + offA[i]);
            bh[i] = *(const bfrag*)(&Bh[cur][0] + offB[i]);
            bl[i] = *(const bfrag*)(&Bl[cur][0] + offB[i]);
        }
        #pragma unroll
        for (int mt = 0; mt < 4; mt++) {
            #pragma unroll
            for (int nt = 0; nt < 4; nt++) {
                ffrag a = acc[mt * 4 + nt];
                a = __builtin_amdgcn_mfma_f32_16x16x32_bf16(ah[mt], bh[nt], a, 0, 0, 0);
                a = __builtin_amdgcn_mfma_f32_16x16x32_bf16(ah[mt], bl[nt], a, 0, 0, 0);
                a = __builtin_amdgcn_mfma_f32_16x16x32_bf16(al[mt], bh[nt], a, 0, 0, 0);
                acc[mt * 4 + nt] = a;
            }
        }
        __builtin_amdgcn_s_barrier();
        cur ^= 1;
    }
    #undef STAGE3

    #pragma unroll
    for (int mt = 0; mt < 4; mt++) {
        #pragma unroll
        for (int nt = 0; nt < 4; nt++) {
            ffrag v = acc[mt * 4 + nt];
            int col = n0 + wn * 64 + nt * 16 + fr;
            int row0 = m0 + wm * 64 + mt * 16 + q * 4;
            #pragma unroll
            for (int j = 0; j < 4; j++)
                Cf[(long)(row0 + j) * N + col] = v[j];
        }
    }
}

static inline void ggemm(hipStream_t st, const u16* A, const u16* Bt,
    float* Cf, u16* Ch, int M, int N, int K, int batch,
    long sA, long sB, long sC,
    const float* bias, const float* res, const float* rs, int rss,
    int accum, int gelu)
{
    dim3 g(N / 128, M / 128, batch), b(256);
    gemm_mfma<<<g, b, 0, st>>>(A, Bt, Cf, Ch, M, N, K, sA, sB, sC,
                               bias, res, rs, rss, accum, gelu);
}

static inline void ggemm3(hipStream_t st, const u16* Ahi, const u16* Alo,
    const u16* Bhi, const u16* Blo, float* Cf, int M, int N, int K)
{
    dim3 g(N / 128, M / 128, 1), b(256);
    gemm3_mfma<<<g, b, 0, st>>>(Ahi, Alo, Bhi, Blo, Cf, M, N, K);
}

// ---------------------------------------------------------------------------
// Sparse MoE FFN, batched across ALL experts in z. Depth-3 prefetch ring.
// ---------------------------------------------------------------------------
__global__ __launch_bounds__(256) void moe_w1(
    const u16* __restrict__ Xa, const u16* __restrict__ Xb,
    const u16* __restrict__ W1a, const u16* __restrict__ W1b,
    u16* __restrict__ ffp,
    const int* __restrict__ idxAll, const int* __restrict__ cntAll,
    const int* __restrict__ offAll, int N, int K)
{
    const int z = blockIdx.z;
    const int m0 = blockIdx.y * 128;
    if (m0 >= cntAll[z]) return;
    const int* idx = idxAll + z * NTOK;
    const u16* X  = (z < NA) ? (Xa + (long)z * NTOK * DD) : Xb;
    const u16* Wt = (z < 4) ? (W1a + (long)z * W1SZ) : (W1b + (long)(z - 4) * W1SZ);
    u16* ff = ffp + (long)offAll[z] * N;

    __shared__ u16 As[3][4096];
    __shared__ u16 Bs[3][4096];
    const int tid = threadIdx.x;
    const int w = tid >> 6, l = tid & 63;
    const int wm = w >> 1, wn = w & 1;
    const int n0 = blockIdx.x * 128;
    const int c0 = 2 * w, c1 = c0 + 1;
    const int rl0 = c0 * 16 + (l >> 2), rl1 = c1 * 16 + (l >> 2);
    const int p = l & 3;
    const int gb0 = p ^ ((rl0 ^ (rl0 >> 2)) & 3);
    const int gb1 = p ^ ((rl1 ^ (rl1 >> 2)) & 3);
    const int t0 = idx[m0 + rl0], t1 = idx[m0 + rl1];
    const u16* gA0 = X + (long)t0 * K + gb0 * 8;
    const u16* gA1 = X + (long)t1 * K + gb1 * 8;
    const u16* gB0 = Wt + (long)(n0 + rl0) * K + gb0 * 8;
    const u16* gB1 = Wt + (long)(n0 + rl1) * K + gb1 * 8;
    const int d0 = c0 * 512, d1 = c1 * 512;
    const int q = l >> 4, fr = l & 15;
    int offA[4], offB[4];
    #pragma unroll
    for (int t = 0; t < 4; t++) {
        int ra = wm * 64 + t * 16 + fr;
        offA[t] = ra * 32 + (q ^ ((ra ^ (ra >> 2)) & 3)) * 8;
        int rb = wn * 64 + t * 16 + fr;
        offB[t] = rb * 32 + (q ^ ((rb ^ (rb >> 2)) & 3)) * 8;
    }
    ffrag acc[16];
    #pragma unroll
    for (int i = 0; i < 16; i++) acc[i] = (ffrag){0.f, 0.f, 0.f, 0.f};

    const int nsteps = K >> 5;
    #define STAGEM(bi, k0) do { \
        gload16(gA0 + (k0), &As[bi][d0]); \
        gload16(gA1 + (k0), &As[bi][d1]); \
        gload16(gB0 + (k0), &Bs[bi][d0]); \
        gload16(gB1 + (k0), &Bs[bi][d1]); } while (0)

    STAGEM(0, 0);
    STAGEM(1, 32);
    int cur = 0;
    for (int t = 0; t < nsteps; ++t) {
        int rem = nsteps - 1 - t;
        if (rem >= 2) {
            int nb = cur + 2; if (nb >= 3) nb -= 3;
            STAGEM(nb, (t + 2) << 5);
            asm volatile("s_waitcnt vmcnt(8)" ::: "memory");
        } else if (rem == 1) {
            asm volatile("s_waitcnt vmcnt(4)" ::: "memory");
        } else {
            asm volatile("s_waitcnt vmcnt(0)" ::: "memory");
        }
        __builtin_amdgcn_s_barrier();
        bfrag af[4], bf[4];
        #pragma unroll
        for (int i = 0; i < 4; i++) {
            af[i] = *(const bfrag*)(&As[cur][0] + offA[i]);
            bf[i] = *(const bfrag*)(&Bs[cur][0] + offB[i]);
        }
        #pragma unroll
        for (int mt = 0; mt < 4; mt++)
            #pragma unroll
            for (int nt = 0; nt < 4; nt++)
                acc[mt * 4 + nt] = __builtin_amdgcn_mfma_f32_16x16x32_bf16(
                    af[mt], bf[nt], acc[mt * 4 + nt], 0, 0, 0);
        __builtin_amdgcn_s_barrier();
        cur = (cur == 2) ? 0 : cur + 1;
    }
    #undef STAGEM

    #pragma unroll
    for (int mt = 0; mt < 4; mt++)
        #pragma unroll
        for (int nt = 0; nt < 4; nt++) {
            ffrag v = acc[mt * 4 + nt];
            int col = n0 + wn * 64 + nt * 16 + fr;
            int row0 = m0 + wm * 64 + mt * 16 + q * 4;
            #pragma unroll
            for (int j = 0; j < 4; j++)
                ff[(long)(row0 + j) * N + col] = f2bf(gelu_f(v[j]));
        }
}

__global__ __launch_bounds__(256) void moe_w2(
    const u16* __restrict__ ffp,
    const u16* __restrict__ W2a, const u16* __restrict__ W2b,
    float* __restrict__ out,
    const int* __restrict__ idxAll, const float* __restrict__ gvAll,
    const int* __restrict__ cntAll, const int* __restrict__ offAll,
    int N, int K)
{
    const int z = blockIdx.z;
    const int cnt = cntAll[z];
    const int m0 = blockIdx.y * 128;
    if (m0 >= cnt) return;
    const int* idx = idxAll + z * NTOK;
    const float* gval = gvAll + z * NTOK;
    const u16* Aseg = ffp + (long)offAll[z] * K;
    const u16* Wt = (z < 4) ? (W2a + (long)z * W1SZ) : (W2b + (long)(z - 4) * W1SZ);

    __shared__ u16 As[3][4096];
    __shared__ u16 Bs[3][4096];
    const int tid = threadIdx.x;
    const int w = tid >> 6, l = tid & 63;
    const int wm = w >> 1, wn = w & 1;
    const int n0 = blockIdx.x * 128;
    const int c0 = 2 * w, c1 = c0 + 1;
    const int rl0 = c0 * 16 + (l >> 2), rl1 = c1 * 16 + (l >> 2);
    const int p = l & 3;
    const int gb0 = p ^ ((rl0 ^ (rl0 >> 2)) & 3);
    const int gb1 = p ^ ((rl1 ^ (rl1 >> 2)) & 3);
    const u16* gA0 = Aseg + (long)(m0 + rl0) * K + gb0 * 8;
    const u16* gA1 = Aseg + (long)(m0 + rl1) * K + gb1 * 8;
    const u16* gB0 = Wt + (long)(n0 + rl0) * K + gb0 * 8;
    const u16* gB1 = Wt + (long)(n0 + rl1) * K + gb1 * 8;
    const int d0 = c0 * 512, d1 = c1 * 512;
    const int q = l >> 4, fr = l & 15;
    int offA[4], offB[4];
    #pragma unroll
    for (int t = 0; t < 4; t++) {
        int ra = wm * 64 + t * 16 + fr;
        offA[t] = ra * 32 + (q ^ ((ra ^ (ra >> 2)) & 3)) * 8;
        int rb = wn * 64 + t * 16 + fr;
        offB[t] = rb * 32 + (q ^ ((rb ^ (rb >> 2)) & 3)) * 8;
    }
    ffrag acc[16];
    #pragma unroll
    for (int i = 0; i < 16; i++) acc[i] = (ffrag){0.f, 0.f, 0.f, 0.f};

    const int nsteps = K >> 5;
    #define STAGEW(bi, k0) do { \
        gload16(gA0 + (k0), &As[bi][d0]); \
        gload16(gA1 + (k0), &As[bi][d1]); \
        gload16(gB0 + (k0), &Bs[bi][d0]); \
        gload16(gB1 + (k0), &Bs[bi][d1]); } while (0)

    STAGEW(0, 0);
    STAGEW(1, 32);
    int cur = 0;
    for (int t = 0; t < nsteps; ++t) {
        int rem = nsteps - 1 - t;
        if (rem >= 2) {
            int nb = cur + 2; if (nb >= 3) nb -= 3;
            STAGEW(nb, (t + 2) << 5);
            asm volatile("s_waitcnt vmcnt(8)" ::: "memory");
        } else if (rem == 1) {
            asm volatile("s_waitcnt vmcnt(4)" ::: "memory");
        } else {
            asm volatile("s_waitcnt vmcnt(0)" ::: "memory");
        }
        __builtin_amdgcn_s_barrier();
        bfrag af[4], bf[4];
        #pragma unroll
        for (int i = 0; i < 4; i++) {
            af[i] = *(const bfrag*)(&As[cur][0] + offA[i]);
            bf[i] = *(const bfrag*)(&Bs[cur][0] + offB[i]);
        }
        #pragma unroll
        for (int mt = 0; mt < 4; mt++)
            #pragma unroll
            for (int nt = 0; nt < 4; nt++)
                acc[mt * 4 + nt] = __builtin_amdgcn_mfma_f32_16x16x32_bf16(
                    af[mt], bf[nt], acc[mt * 4 + nt], 0, 0, 0);
        __builtin_amdgcn_s_barrier();
        cur = (cur == 2) ? 0 : cur + 1;
    }
    #undef STAGEW

    #pragma unroll
    for (int mt = 0; mt < 4; mt++)
        #pragma unroll
        for (int nt = 0; nt < 4; nt++) {
            ffrag v = acc[mt * 4 + nt];
            int col = n0 + wn * 64 + nt * 16 + fr;
            int row0 = m0 + wm * 64 + mt * 16 + q * 4;
            #pragma unroll
            for (int j = 0; j < 4; j++) {
                int m = row0 + j;
                if (m < cnt)
                    atomicAdd(&out[(long)idx[m] * N + col], gval[m] * v[j]);
            }
        }
}

__global__ __launch_bounds__(256) void moe_zero(int* __restrict__ idx, int* __restrict__ cnt)
{
    int i = blockIdx.x * 256 + threadIdx.x;
    if (i < NE * NTOK) idx[i] = 0;
    if (i < NE) cnt[i] = 0;
}

__global__ __launch_bounds__(256) void moe_build(
    const float* __restrict__ gates, int* __restrict__ idx,
    float* __restrict__ gval, int* __restrict__ cnt)
{
    int t = blockIdx.x * 256 + threadIdx.x;
    #pragma unroll
    for (int e = 0; e < NE; e++) {
        float g = gates[(long)t * NE + e];
        if (g > 0.f) {
            int ppos = atomicAdd(&cnt[e], 1);
            idx[e * NTOK + ppos] = t;
            gval[e * NTOK + ppos] = g;
        }
    }
}

__global__ __launch_bounds__(64) void moe_off(
    const int* __restrict__ cnt, int* __restrict__ off)
{
    if (threadIdx.x == 0) {
        int o = 0;
        for (int e = 0; e < NE; e++) { off[e] = o; o += (cnt[e] + 127) & ~127; }
    }
}

// ---------------------------------------------------------------------------
// Weight convert+transpose kernels (z-batched: src/dst strides per z)
// ---------------------------------------------------------------------------
__global__ __launch_bounds__(256) void convT_kernel(
    const float* __restrict__ src, u16* __restrict__ dst, int K, int N,
    long sS, long sD)
{
    __shared__ float t[32][33];
    src += (long)blockIdx.z * sS;
    dst += (long)blockIdx.z * sD;
    int n0 = blockIdx.x * 32, k0 = blockIdx.y * 32;
    int tx = threadIdx.x & 31, ty = threadIdx.x >> 5;
    #pragma unroll
    for (int j = 0; j < 4; j++)
        t[ty + j * 8][tx] = src[(long)(k0 + ty + j * 8) * N + n0 + tx];
    __syncthreads();
    #pragma unroll
    for (int j = 0; j < 4; j++)
        dst[(long)(n0 + ty + j * 8) * K + k0 + tx] = f2bf(t[tx][ty + j * 8]);
}

__global__ __launch_bounds__(256) void convT2_kernel(
    const float* __restrict__ src, u16* __restrict__ dhi, u16* __restrict__ dlo,
    int K, int N)
{
    __shared__ float t[32][33];
    int n0 = blockIdx.x * 32, k0 = blockIdx.y * 32;
    int tx = threadIdx.x & 31, ty = threadIdx.x >> 5;
    #pragma unroll
    for (int j = 0; j < 4; j++)
        t[ty + j * 8][tx] = src[(long)(k0 + ty + j * 8) * N + n0 + tx];
    __syncthreads();
    #pragma unroll
    for (int j = 0; j < 4; j++) {
        float v = t[tx][ty + j * 8];
        u16 hi, lo; split_bf(v, hi, lo);
        long o = (long)(n0 + ty + j * 8) * K + k0 + tx;
        dhi[o] = hi; dlo[o] = lo;
    }
}

__global__ __launch_bounds__(256) void conv_kernel(
    const float* __restrict__ s, u16* __restrict__ d)
{
    int i = (blockIdx.x * 256 + threadIdx.x) * 4;
    float4 v = *(const float4*)(s + i);
    ushort4 o;
    o.x = f2bf(v.x); o.y = f2bf(v.y); o.z = f2bf(v.z); o.w = f2bf(v.w);
    *(ushort4*)(d + i) = o;
}

// ---------------------------------------------------------------------------
// LayerNorm -> bf16 hi/lo
// ---------------------------------------------------------------------------
__global__ __launch_bounds__(256) void ln_kernel(
    const float* __restrict__ x, const float* __restrict__ g,
    const float* __restrict__ b, u16* __restrict__ hhi, u16* __restrict__ hlo)
{
    int token = blockIdx.x;
    int tid = threadIdx.x;
    const float* xr = x + (long)token * DD;
    float4 xv = *(const float4*)(xr + tid * 4);
    float s  = xv.x + xv.y + xv.z + xv.w;
    float sq = xv.x*xv.x + xv.y*xv.y + xv.z*xv.z + xv.w*xv.w;
    #pragma unroll
    for (int off = 32; off; off >>= 1) {
        s  += __shfl_xor(s, off);
        sq += __shfl_xor(sq, off);
    }
    __shared__ float ws[4], wq[4];
    int wid = tid >> 6, lane = tid & 63;
    if (lane == 0) { ws[wid] = s; wq[wid] = sq; }
    __syncthreads();
    s  = ws[0] + ws[1] + ws[2] + ws[3];
    sq = wq[0] + wq[1] + wq[2] + wq[3];
    float mu  = s * (1.f / DD);
    float var = sq * (1.f / DD) - mu * mu;
    float inv = rsqrtf(var + 1e-5f);
    float4 gv = *(const float4*)(g + tid * 4);
    float4 bv = *(const float4*)(b + tid * 4);
    float o[4];
    o[0] = (xv.x - mu) * inv * gv.x + bv.x;
    o[1] = (xv.y - mu) * inv * gv.y + bv.y;
    o[2] = (xv.z - mu) * inv * gv.z + bv.z;
    o[3] = (xv.w - mu) * inv * gv.w + bv.w;
    ushort4 oh, ol;
    split_bf(o[0], oh.x, ol.x); split_bf(o[1], oh.y, ol.y);
    split_bf(o[2], oh.z, ol.z); split_bf(o[3], oh.w, ol.w);
    *(ushort4*)(hhi + (long)token * DD + tid * 4) = oh;
    *(ushort4*)(hlo + (long)token * DD + tid * 4) = ol;
}

// ---------------------------------------------------------------------------
// SSM scan, 3-pass chunked
// ---------------------------------------------------------------------------
__global__ __launch_bounds__(256) void scan_p1(
    const float* __restrict__ u, const float* __restrict__ ssma,
    float* __restrict__ part)
{
    int i = blockIdx.x * 256 + threadIdx.x;
    int c = i & 2047, ch = (i >> 11) & 7, b = i >> 14;
    float a = 1.f / (1.f + expf(-ssma[c])), om = 1.f - a;
    const float* ux = u + (long)b * SS * (2 * DI) + DI + c;
    float h = 0.f;
    int t0 = ch * 128;
    #pragma unroll 4
    for (int t = t0; t < t0 + 128; ++t) h = a * h + om * ux[(long)t * (2 * DI)];
    part[i] = h;
}

__global__ __launch_bounds__(256) void scan_p2(
    const float* __restrict__ ssma, const float* __restrict__ part,
    float* __restrict__ init)
{
    int j = blockIdx.x * 256 + threadIdx.x;
    int c = j & 2047, b = j >> 11;
    float a = 1.f / (1.f + expf(-ssma[c]));
    float ap = a;
    #pragma unroll
    for (int i = 0; i < 7; i++) ap *= ap;
    float carry = 0.f;
    int base = b * 16384 + c;
    #pragma unroll
    for (int ch = 0; ch < 8; ch++) {
        init[base + ch * 2048] = carry;
        carry = ap * carry + part[base + ch * 2048];
    }
}

__global__ __launch_bounds__(256) void scan_p3(
    const float* __restrict__ u, const float* __restrict__ ssma,
    const float* __restrict__ init,
    u16* __restrict__ ihi, u16* __restrict__ ilo)
{
    int i = blockIdx.x * 256 + threadIdx.x;
    int c = i & 2047, ch = (i >> 11) & 7, b = i >> 14;
    float a = 1.f / (1.f + expf(-ssma[c])), om = 1.f - a;
    const float* uz = u + (long)b * SS * (2 * DI) + c;
    long obase = (long)b * SS * DI + c;
    float h = init[i];
    int t0 = ch * 128;
    #pragma unroll 2
    for (int t = t0; t < t0 + 128; ++t) {
        float z  = uz[(long)t * (2 * DI)];
        float xv = uz[(long)t * (2 * DI) + DI];
        h = a * h + om * xv;
        float sz = z / (1.f + expf(-z));
        u16 hi, lo; split_bf(h * sz, hi, lo);
        ihi[obase + (long)t * DI] = hi;
        ilo[obase + (long)t * DI] = lo;
    }
}

// ---------------------------------------------------------------------------
// QKV prep: fp32 qkv -> Q/K hi/lo [bh][s][64], Vt hi/lo [bh][64][s]
// ---------------------------------------------------------------------------
__global__ __launch_bounds__(256) void qk_prep(
    const float* __restrict__ qkv,
    u16* __restrict__ Qhi, u16* __restrict__ Qlo,
    u16* __restrict__ Khi, u16* __restrict__ Klo)
{
    int tok = blockIdx.x * 4 + (threadIdx.x >> 6);
    int l = threadIdx.x & 63;
    int b = tok >> 10, s = tok & 1023;
    const float* src = qkv + (long)tok * 3072;
    #pragma unroll
    for (int h = 0; h < 16; h++) {
        long dst = ((long)(b * 16 + h) * 1024 + s) * 64 + l;
        u16 hi, lo;
        split_bf(src[h * 64 + l], hi, lo);
        Qhi[dst] = hi; Qlo[dst] = lo;
        split_bf(src[1024 + h * 64 + l], hi, lo);
        Khi[dst] = hi; Klo[dst] = lo;
    }
}

__global__ __launch_bounds__(256) void v_prep(
    const float* __restrict__ qkv, u16* __restrict__ Vthi, u16* __restrict__ Vtlo)
{
    __shared__ float t[64][65];
    int st = blockIdx.x, bh = blockIdx.y;
    int b = bh >> 4, h = bh & 15;
    int tid = threadIdx.x;
    #pragma unroll
    for (int i = 0; i < 16; i++) {
        int e = tid + i * 256;
        int sl = e >> 6, d = e & 63;
        t[sl][d] = qkv[((long)(b * 1024 + st * 64 + sl)) * 3072 + 2048 + h * 64 + d];
    }
    __syncthreads();
    #pragma unroll
    for (int i = 0; i < 16; i++) {
        int e = tid + i * 256;
        int d = e >> 6, sl = e & 63;
        float v = t[sl][d];
        u16 hi, lo; split_bf(v, hi, lo);
        long o = ((long)bh * 64 + d) * 1024 + st * 64 + sl;
        Vthi[o] = hi; Vtlo[o] = lo;
    }
}

// ---------------------------------------------------------------------------
// MFMA split-bf16 causal flash attention. 4 waves, q-tile 64, K-tiles of 64.
// K double-buffered LDS + V staged late, counted vmcnt (GEMM-style pipeline).
// LDS = 80KB: Q 16 + K 2x16 + V 16 + P 16.
// ---------------------------------------------------------------------------
__global__ __launch_bounds__(256) void flash_mfma(
    const u16* __restrict__ Qhi, const u16* __restrict__ Qlo,
    const u16* __restrict__ Khi, const u16* __restrict__ Klo,
    const u16* __restrict__ Vthi, const u16* __restrict__ Vtlo,
    u16* __restrict__ aohi, u16* __restrict__ aolo)
{
    __shared__ u16 Qh[4096], Ql[4096];
    __shared__ u16 Kh[2][4096], Kl[2][4096];
    __shared__ u16 Vh[4096], Vl[4096];
    __shared__ u16 Ph[4][1024], Pl[4][1024];
    const int qt = (SS / 64 - 1) - blockIdx.x, bh = blockIdx.y;
    const int tid = threadIdx.x, w = tid >> 6, l = tid & 63;
    const int q0 = qt * 64;
    const int lr = l >> 3, ps = l & 7;
    const int cg = l & 15, quad = l >> 4;

    // prologue: stage Q, K[0] -> Kbuf0, V[0]  (12 loads/thread)
    #pragma unroll
    for (int cc = 0; cc < 2; cc++) {
        int c = 2 * w + cc;
        int r = c * 8 + lr;
        int pl = ps ^ (r & 7);
        long gq = ((long)bh * 1024 + q0 + r) * 64 + pl * 8;
        long gk = ((long)bh * 1024 + r) * 64 + pl * 8;
        long gv = ((long)bh * 64 + r) * 1024 + pl * 8;
        gload16(Qhi + gq, Qh + c * 512 + l * 8);
        gload16(Qlo + gq, Ql + c * 512 + l * 8);
        gload16(Khi + gk, Kh[0] + c * 512 + l * 8);
        gload16(Klo + gk, Kl[0] + c * 512 + l * 8);
        gload16(Vthi + gv, Vh + c * 512 + l * 8);
        gload16(Vtlo + gv, Vl + c * 512 + l * 8);
    }
    asm volatile("s_waitcnt vmcnt(0)" ::: "memory");
    __builtin_amdgcn_s_barrier();

    const int qrow = w * 16 + cg;
    const int offQ0 = flds(qrow, quad), offQ1 = flds(qrow, 4 + quad);
    bfrag qh0 = *(const bfrag*)(Qh + offQ0);
    bfrag qh1 = *(const bfrag*)(Qh + offQ1);
    bfrag ql0 = *(const bfrag*)(Ql + offQ0);
    bfrag ql1 = *(const bfrag*)(Ql + offQ1);

    ffrag O[4];
    #pragma unroll
    for (int i = 0; i < 4; i++) O[i] = (ffrag){0.f, 0.f, 0.f, 0.f};
    float mrun[4], lrun[4];
    #pragma unroll
    for (int j = 0; j < 4; j++) { mrun[j] = -1e30f; lrun[j] = 0.f; }

    int cur = 0;
    for (int kt = 0; kt <= qt; kt++) {
        // stage K[kt+1] into the other K buffer (4 loads)
        if (kt < qt) {
            int k0n = (kt + 1) * 64;
            #pragma unroll
            for (int cc = 0; cc < 2; cc++) {
                int c = 2 * w + cc;
                int r = c * 8 + lr;
                int pl = ps ^ (r & 7);
                long gk = ((long)bh * 1024 + k0n + r) * 64 + pl * 8;
                gload16(Khi + gk, Kh[cur ^ 1] + c * 512 + l * 8);
                gload16(Klo + gk, Kl[cur ^ 1] + c * 512 + l * 8);
            }
            // wait for everything older than the 4 just-issued loads
            asm volatile("s_waitcnt vmcnt(4)" ::: "memory");
        } else {
            asm volatile("s_waitcnt vmcnt(0)" ::: "memory");
        }
        __builtin_amdgcn_s_barrier();

        const u16* KhC = Kh[cur];
        const u16* KlC = Kl[cur];
        float s[4][4];
        #pragma unroll
        for (int nt = 0; nt < 4; nt++) {
            ffrag sc = (ffrag){0.f, 0.f, 0.f, 0.f};
            int kr = nt * 16 + cg;
            bfrag kh0 = *(const bfrag*)(KhC + flds(kr, quad));
            bfrag kh1 = *(const bfrag*)(KhC + flds(kr, 4 + quad));
            bfrag kl0 = *(const bfrag*)(KlC + flds(kr, quad));
            bfrag kl1 = *(const bfrag*)(KlC + flds(kr, 4 + quad));
            sc = __builtin_amdgcn_mfma_f32_16x16x32_bf16(qh0, kh0, sc, 0, 0, 0);
            sc = __builtin_amdgcn_mfma_f32_16x16x32_bf16(qh1, kh1, sc, 0, 0, 0);
            sc = __builtin_amdgcn_mfma_f32_16x16x32_bf16(qh0, kl0, sc, 0, 0, 0);
            sc = __builtin_amdgcn_mfma_f32_16x16x32_bf16(qh1, kl1, sc, 0, 0, 0);
            sc = __builtin_amdgcn_mfma_f32_16x16x32_bf16(ql0, kh0, sc, 0, 0, 0);
            sc = __builtin_amdgcn_mfma_f32_16x16x32_bf16(ql1, kh1, sc, 0, 0, 0);
            bool last = (kt == qt);
            #pragma unroll
            for (int j = 0; j < 4; j++) {
                float v = sc[j] * 0.125f;
                if (last && (nt * 16 + cg > w * 16 + quad * 4 + j)) v = -1e30f;
                s[nt][j] = v;
            }
        }
        #pragma unroll
        for (int j = 0; j < 4; j++) {
            float rm = fmaxf(fmaxf(s[0][j], s[1][j]), fmaxf(s[2][j], s[3][j]));
            rm = fmaxf(rm, __shfl_xor(rm, 1));
            rm = fmaxf(rm, __shfl_xor(rm, 2));
            rm = fmaxf(rm, __shfl_xor(rm, 4));
            rm = fmaxf(rm, __shfl_xor(rm, 8));
            float mn = fmaxf(mrun[j], rm);
            float alpha = __expf(mrun[j] - mn);
            float rs = 0.f;
            #pragma unroll
            for (int nt = 0; nt < 4; nt++) {
                float pv = __expf(s[nt][j] - mn);
                s[nt][j] = pv;
                rs += pv;
            }
            rs += __shfl_xor(rs, 1);
            rs += __shfl_xor(rs, 2);
            rs += __shfl_xor(rs, 4);
            rs += __shfl_xor(rs, 8);
            lrun[j] = lrun[j] * alpha + rs;
            mrun[j] = mn;
            #pragma unroll
            for (int ct = 0; ct < 4; ct++) O[ct][j] *= alpha;
        }
        // P (C-layout) -> per-wave LDS, split hi/lo, swizzled for A-frag reads
        #pragma unroll
        for (int nt = 0; nt < 4; nt++)
            #pragma unroll
            for (int j = 0; j < 4; j++) {
                int row = quad * 4 + j, col = nt * 16 + cg;
                int addr = row * 64 + (((col >> 3) ^ (row & 7)) << 3) + (col & 7);
                float pv = s[nt][j];
                u16 phv = f2bf(pv);
                float pf2 = __uint_as_float((unsigned)phv << 16);
                Ph[w][addr] = phv;
                Pl[w][addr] = f2bf(pv - pf2);
            }
        bfrag p0h = *(const bfrag*)(&Ph[w][0] + flds(cg, quad));
        bfrag p1h = *(const bfrag*)(&Ph[w][0] + flds(cg, 4 + quad));
        bfrag p0l = *(const bfrag*)(&Pl[w][0] + flds(cg, quad));
        bfrag p1l = *(const bfrag*)(&Pl[w][0] + flds(cg, 4 + quad));
        #pragma unroll
        for (int ct = 0; ct < 4; ct++) {
            int vr = ct * 16 + cg;
            bfrag vh0 = *(const bfrag*)(Vh + flds(vr, quad));
            bfrag vh1 = *(const bfrag*)(Vh + flds(vr, 4 + quad));
            bfrag vl0 = *(const bfrag*)(Vl + flds(vr, quad));
            bfrag vl1 = *(const bfrag*)(Vl + flds(vr, 4 + quad));
            O[ct] = __builtin_amdgcn_mfma_f32_16x16x32_bf16(p0h, vh0, O[ct], 0, 0, 0);
            O[ct] = __builtin_amdgcn_mfma_f32_16x16x32_bf16(p1h, vh1, O[ct], 0, 0, 0);
            O[ct] = __builtin_amdgcn_mfma_f32_16x16x32_bf16(p0h, vl0, O[ct], 0, 0, 0);
            O[ct] = __builtin_amdgcn_mfma_f32_16x16x32_bf16(p1h, vl1, O[ct], 0, 0, 0);
            O[ct] = __builtin_amdgcn_mfma_f32_16x16x32_bf16(p0l, vh0, O[ct], 0, 0, 0);
            O[ct] = __builtin_amdgcn_mfma_f32_16x16x32_bf16(p1l, vh1, O[ct], 0, 0, 0);
        }
        __builtin_amdgcn_s_barrier();
        // stage V[kt+1] into the (single) V buffer; lands before next PV,
        // covered by the vmcnt(4) + K-stage + QK + softmax of next iteration
        if (kt < qt) {
            int k0n = (kt + 1) * 64;
            #pragma unroll
            for (int cc = 0; cc < 2; cc++) {
                int c = 2 * w + cc;
                int r = c * 8 + lr;
                int pl = ps ^ (r & 7);
                long gv = ((long)bh * 64 + r) * 1024 + k0n + pl * 8;
                gload16(Vthi + gv, Vh + c * 512 + l * 8);
                gload16(Vtlo + gv, Vl + c * 512 + l * 8);
            }
        }
        cur ^= 1;
    }
    int b = bh >> 4, h = bh & 15;
    #pragma unroll
    for (int j = 0; j < 4; j++) {
        float inv = 1.f / lrun[j];
        int srow = q0 + w * 16 + quad * 4 + j;
        long base = ((long)(b * 1024 + srow)) * 1024 + h * 64 + cg;
        #pragma unroll
        for (int ct = 0; ct < 4; ct++) {
            float v = O[ct][j] * inv;
            u16 hi, lo; split_bf(v, hi, lo);
            aohi[base + ct * 16] = hi;
            aolo[base + ct * 16] = lo;
        }
    }
}

// ---------------------------------------------------------------------------
// x1 combine, router, softmax512
// ---------------------------------------------------------------------------
__global__ __launch_bounds__(256) void combine_kernel(
    const float* __restrict__ x, const float* __restrict__ ssm,
    const float* __restrict__ attn, const float* __restrict__ bs,
    const float* __restrict__ ba, float* __restrict__ x1, u16* __restrict__ x1h)
{
    int i = (blockIdx.x * 256 + threadIdx.x) * 4;
    int d = i & (DD - 1);
    float4 xv = *(const float4*)(x + i);
    float4 sv = *(const float4*)(ssm + i);
    float4 av = *(const float4*)(attn + i);
    float4 b1 = *(const float4*)(bs + d);
    float4 b2 = *(const float4*)(ba + d);
    float4 o;
    o.x = xv.x + b1.x * sv.x + b2.x * av.x;
    o.y = xv.y + b1.y * sv.y + b2.y * av.y;
    o.z = xv.z + b1.z * sv.z + b2.z * av.z;
    o.w = xv.w + b1.w * sv.w + b2.w * av.w;
    *(float4*)(x1 + i) = o;
    ushort4 oh;
    oh.x = f2bf(o.x); oh.y = f2bf(o.y); oh.z = f2bf(o.z); oh.w = f2bf(o.w);
    *(ushort4*)(x1h + i) = oh;
}

__global__ __launch_bounds__(256) void router_kernel(
    const float* __restrict__ x1, const int* __restrict__ enc_avail,
    const float* __restrict__ rW, const float* __restrict__ rb,
    float* __restrict__ gates)
{
    int token = blockIdx.x * 4 + (threadIdx.x >> 6);
    int lane = threadIdx.x & 63;
    int b = token >> 10;
    float acc[NE];
    #pragma unroll
    for (int e = 0; e < NE; e++) acc[e] = 0.f;
    const float* xrow = x1 + (long)token * DD;
    for (int d = lane; d < DD; d += 64) {
        float xv = xrow[d];
        const float* w = rW + (long)d * NE;
        #pragma unroll
        for (int e = 0; e < NE; e++) acc[e] += xv * w[e];
    }
    #pragma unroll
    for (int e = 0; e < NE; e++) {
        #pragma unroll
        for (int off = 32; off; off >>= 1) acc[e] += __shfl_xor(acc[e], off);
    }
    if (lane == 0) {
        int avail = enc_avail[b];
        float av = (float)avail;
        float lg[NE], pr[NE];
        #pragma unroll
        for (int e = 0; e < NE; e++) lg[e] = acc[e] + av * rW[(long)DD * NE + e] + rb[e];
        float mx = lg[0];
        #pragma unroll
        for (int e = 1; e < NE; e++) mx = fmaxf(mx, lg[e]);
        float sum = 0.f;
        #pragma unroll
        for (int e = 0; e < NE; e++) { pr[e] = expf(lg[e] - mx); sum += pr[e]; }
        float isum = 1.f / sum;
        #pragma unroll
        for (int e = 0; e < NE; e++) pr[e] *= isum;
        int i1 = 0;
        #pragma unroll
        for (int e = 1; e < NE; e++) if (pr[e] > pr[i1]) i1 = e;
        int i2 = (i1 == 0) ? 1 : 0;
        #pragma unroll
        for (int e = 0; e < NE; e++) if (e != i1 && pr[e] > pr[i2]) i2 = e;
        float g[NE];
        #pragma unroll
        for (int e = 0; e < NE; e++) g[e] = 0.f;
        g[i1] = pr[i1]; g[i2] = pr[i2];
        float s1 = g[i1] + g[i2] + 1e-9f;
        #pragma unroll
        for (int e = 0; e < NE; e++) g[e] /= s1;
        if (avail == 0) { g[0] = 0.f; g[1] = 0.f; }
        float s2 = 1e-6f;
        #pragma unroll
        for (int e = 0; e < NE; e++) s2 += g[e];
        float is2 = 1.f / s2;
        #pragma unroll
        for (int e = 0; e < NE; e++) gates[(long)token * NE + e] = g[e] * is2;
    }
}

__global__ __launch_bounds__(256) void softmax512_kernel(
    const float* __restrict__ sA, u16* __restrict__ pA, float scale)
{
    int row = blockIdx.x * 4 + (threadIdx.x >> 6);
    int lane = threadIdx.x & 63;
    const float* r = sA + (long)row * ENCS;
    u16* o = pA + (long)row * ENCS;
    float v[8];
    #pragma unroll
    for (int j = 0; j < 8; j++) v[j] = r[lane + j * 64] * scale;
    float mx = v[0];
    #pragma unroll
    for (int j = 1; j < 8; j++) mx = fmaxf(mx, v[j]);
    #pragma unroll
    for (int off = 32; off; off >>= 1) mx = fmaxf(mx, __shfl_xor(mx, off));
    float sum = 0.f;
    #pragma unroll
    for (int j = 0; j < 8; j++) { v[j] = __expf(v[j] - mx); sum += v[j]; }
    #pragma unroll
    for (int off = 32; off; off >>= 1) sum += __shfl_xor(sum, off);
    float inv = 1.f / sum;
    #pragma unroll
    for (int j = 0; j < 8; j++) o[lane + j * 64] = f2bf(v[j] * inv);
}

// ---------------------------------------------------------------------------
// launch
// ---------------------------------------------------------------------------
extern "C" void kernel_launch(void* const* d_in, const int* in_sizes, int n_in,
                              void* d_out, int out_size, void* d_ws, size_t ws_size,
                              hipStream_t stream) {
    const float* x    = (const float*)d_in[0];
    const float* enc  = (const float*)d_in[1];
    const int*   eav  = (const int*)d_in[4];
    const float* ln_g = (const float*)d_in[5];
    const float* ln_b = (const float*)d_in[6];
    const float* Win  = (const float*)d_in[7];
    const float* ssma = (const float*)d_in[8];
    const float* Wout = (const float*)d_in[9];
    const float* Wqkv = (const float*)d_in[10];
    const float* Wo   = (const float*)d_in[11];
    const float* bSsm = (const float*)d_in[12];
    const float* bAtt = (const float*)d_in[13];
    const float* seW1 = (const float*)d_in[14];
    const float* seb1 = (const float*)d_in[15];
    const float* seW2 = (const float*)d_in[16];
    const float* seb2 = (const float*)d_in[17];
    const float* rW   = (const float*)d_in[18];
    const float* rb   = (const float*)d_in[19];
    const float* eaWq = (const float*)d_in[20];
    const float* eaWk = (const float*)d_in[21];
    const float* eaWv = (const float*)d_in[22];
    const float* eaWo = (const float*)d_in[23];
    const float* eaW1 = (const float*)d_in[24];
    const float* eaW2 = (const float*)d_in[25];
    const float* ebW1 = (const float*)d_in[26];
    const float* ebW2 = (const float*)d_in[27];
    float* out = (float*)d_out;

    // ---- workspace layout (~185.5 MB) ----
    float* F = (float*)d_ws;
    float* f_big  = F;                    // 16,777,216 fl (64MB)
    float* f_ssm  = F + 16777216;         // 4,194,304
    float* f_x1   = F + 20971520;         // 4,194,304 (persists)
    float* f_part = F + 25165824;         // 65,536
    float* f_init = F + 25231360;         // 65,536
    float* f_gate = F + 25296896;         // 32,768
    u16* U = (u16*)(F + 25329664);
    u16* u_h_hi  = U;                     // 4,194,304
    u16* u_h_lo  = U + 4194304;           // 4,194,304 (x1 bf16, persists)
    u16* u_in_hi = U + 8388608;           // 8,388,608
    u16* u_in_lo = U + 16777216;          // 8,388,608
    u16* u_ao_hi = U + 25165824;          // 4,194,304
    u16* u_ao_lo = U + 29360128;          // 4,194,304
    u16* u_wt    = U + 33554432;          // 4,194,304
    u16* u_wt_lo = U + 37748736;          // 4,194,304
    int*   moe_idx = (int*)(U + 41943040);        // 8*4096 ints
    float* moe_gv  = (float*)(moe_idx + NE * NTOK);
    int*   moe_cnt = (int*)(moe_gv + NE * NTOK);  // 8 ints
    int*   moe_offp = moe_cnt + NE;               // 8 ints

    // main-phase aliases
    float* f_u    = f_big;
    float* f_qkv  = f_big;
    float* f_attn = f_big + 12582912;
    u16*   u_ff   = (u16*)f_big;          // shared-FFN intermediate (16MB)
    u16*   u_enc  = u_h_hi + 2097152;     // encoder bf16 (4MB, persists in expert phase)
    u16*   u_x1   = u_h_lo;
    // flash staging buffers
    u16* u_Qhi = u_h_hi, *u_Qlo = u_h_lo;
    u16* u_Khi = u_in_hi, *u_Klo = u_in_hi + 4194304;
    u16* u_Vthi = u_in_lo, *u_Vtlo = u_in_lo + 4194304;

    // expert-phase buffers (all exact-fit, see liveness notes)
    u16*   wq2   = u_wt;                              // 2 x DD*DD
    u16*   wk2   = u_wt_lo;
    u16*   wv2   = (u16*)f_ssm;
    u16*   wo2   = (u16*)f_ssm + 4194304;
    u16*   qA2   = u_ao_hi;                           // 2 x NTOK*DD (spans ao_hi+ao_lo)
    u16*   kA2   = u_in_hi;                           // 2 x 2048*DD
    u16*   vAt2  = u_in_hi + 4194304;                 // 2 x 4 x DD*ENCS
    float* sA2   = (float*)u_in_lo;                   // 8 x SS*ENCS fp32
    u16*   ctx2  = u_in_lo;                           // 8 x SS*DD (after sA2 dead)
    u16*   ffpool = (u16*)f_big;                      // 10240 x DFE rows (40MB)
    u16*   hA2   = (u16*)(f_big + 10485760);          // 2 x NTOK*DD (16MB)
    u16*   pA2   = (u16*)(f_big + 14680064);          // 8 x SS*ENCS bf16 (8MB)
    u16*   w1a   = u_ao_hi;                           // experts 0-3 W1 (after qA2 dead)
    u16*   w1b   = u_in_hi;                           // experts 4-7 W1 (after kA2/vAt2 dead)
    u16*   w2a   = u_wt;                              // experts 0-3 W2 (after wq2/wk2 dead)
    u16*   w2b   = (u16*)f_ssm;                       // experts 4-7 W2 (after wv2/wo2 dead)

    #define CONVT(src, Kd, Nd)  convT_kernel <<<dim3((Nd)/32,(Kd)/32,1), dim3(256), 0, stream>>>(src, u_wt, Kd, Nd, 0, 0)
    #define CONVTB(src, dst, Kd, Nd, nb) convT_kernel<<<dim3((Nd)/32,(Kd)/32,(nb)), dim3(256), 0, stream>>>(src, dst, Kd, Nd, (long)(Kd)*(Nd), (long)(Kd)*(Nd))
    #define CONVT2(src, Kd, Nd) convT2_kernel<<<dim3((Nd)/32,(Kd)/32), dim3(256), 0, stream>>>(src, u_wt, u_wt_lo, Kd, Nd)

    // 1) h = LN(x) (bf16 hi/lo)
    ln_kernel<<<dim3(NTOK), dim3(256), 0, stream>>>(x, ln_g, ln_b, u_h_hi, u_h_lo);
    // 2) u = h @ Win (fused split 3-product GEMM)
    CONVT2(Win, DD, 2 * DI);
    ggemm3(stream, u_h_hi, u_h_lo, u_wt, u_wt_lo, f_u, NTOK, 2 * DI, DD);
    // 3) chunked scan -> inner (bf16 hi/lo)
    scan_p1<<<dim3(256), dim3(256), 0, stream>>>(f_u, ssma, f_part);
    scan_p2<<<dim3(32), dim3(256), 0, stream>>>(ssma, f_part, f_init);
    scan_p3<<<dim3(256), dim3(256), 0, stream>>>(f_u, ssma, f_init, u_in_hi, u_in_lo);
    // 4) ssm_out = inner @ Wout (fused split)
    CONVT2(Wout, DI, DD);
    ggemm3(stream, u_in_hi, u_in_lo, u_wt, u_wt_lo, f_ssm, NTOK, DD, DI);
    // 5) qkv = h @ Wqkv (fused split; overwrites u region)
    CONVT2(Wqkv, DD, 3 * DD);
    ggemm3(stream, u_h_hi, u_h_lo, u_wt, u_wt_lo, f_qkv, NTOK, 3 * DD, DD);
    // 5.5) split qkv into per-head hi/lo layouts
    qk_prep<<<dim3(NTOK / 4), dim3(256), 0, stream>>>(f_qkv, u_Qhi, u_Qlo, u_Khi, u_Klo);
    v_prep<<<dim3(SS / 64, BB * NH), dim3(256), 0, stream>>>(f_qkv, u_Vthi, u_Vtlo);
    // 6) MFMA flash attention -> ao hi/lo
    flash_mfma<<<dim3(SS / 64, BB * NH), dim3(256), 0, stream>>>(
        u_Qhi, u_Qlo, u_Khi, u_Klo, u_Vthi, u_Vtlo, u_ao_hi, u_ao_lo);
    // 7) attn = ao @ Wo (fused split)
    CONVT2(Wo, DD, DD);
    ggemm3(stream, u_ao_hi, u_ao_lo, u_wt, u_wt_lo, f_attn, NTOK, DD, DD);
    // 8) x1 = x + bs*ssm + ba*attn
    combine_kernel<<<dim3(NTOK * DD / 1024), dim3(256), 0, stream>>>(
        x, f_ssm, f_attn, bSsm, bAtt, f_x1, u_x1);
    // 9) router + expert token lists + prefix offsets
    router_kernel<<<dim3(NTOK / 4), dim3(256), 0, stream>>>(f_x1, eav, rW, rb, f_gate);
    moe_zero<<<dim3((NE * NTOK + 255) / 256), dim3(256), 0, stream>>>(moe_idx, moe_cnt);
    moe_build<<<dim3(NTOK / 256), dim3(256), 0, stream>>>(f_gate, moe_idx, moe_gv, moe_cnt);
    moe_off<<<dim3(1), dim3(64), 0, stream>>>(moe_cnt, moe_offp);
    // 10) ff = gelu(x1 @ seW1 + b1) (bf16)
    CONVT(seW1, DD, DFF);
    ggemm(stream, u_x1, u_wt, nullptr, u_ff, NTOK, DFF, DD, 1, 0, 0, 0,
          seb1, nullptr, nullptr, 0, 0, 1);
    // 11) out = x1 + ff @ seW2 + b2 (fp32)
    CONVT(seW2, DFF, DD);
    ggemm(stream, u_ff, u_wt, out, nullptr, NTOK, DD, DFF, 1, 0, 0, 0,
          seb2, f_x1, nullptr, 0, 0, 0);
    // 12) encoder -> bf16
    conv_kernel<<<dim3(BB * ENCS * DD / 1024), dim3(256), 0, stream>>>(enc, u_enc);

    // 13) type-A cross-attention, batched across both experts
    CONVTB(eaWq, wq2, DD, DD, 2);
    CONVTB(eaWk, wk2, DD, DD, 2);
    CONVTB(eaWv, wv2, DD, DD, 2);
    CONVTB(eaWo, wo2, DD, DD, 2);
    // qA[e] = x1 @ Wq[e]   (batch 2)
    ggemm(stream, u_x1, wq2, nullptr, qA2, NTOK, DD, DD, 2,
          0, (long)DD * DD, (long)NTOK * DD, nullptr, nullptr, nullptr, 0, 0, 0);
    // kA[e] = enc @ Wk[e]  (batch 2)
    ggemm(stream, u_enc, wk2, nullptr, kA2, BB * ENCS, DD, DD, 2,
          0, (long)DD * DD, (long)BB * ENCS * DD, nullptr, nullptr, nullptr, 0, 0, 0);
    // vAt[e][b] = (enc[b] @ Wv[e])^T  (2 launches, batch 4 each)
    for (int e = 0; e < NA; ++e)
        ggemm(stream, wv2 + (long)e * DD * DD, u_enc, nullptr,
              vAt2 + (long)e * 4 * DD * ENCS, DD, ENCS, DD, BB,
              0, (long)ENCS * DD, (long)DD * ENCS, nullptr, nullptr, nullptr, 0, 0, 0);
    // sA = qA @ kA^T  (batch 8 = [e][b])
    ggemm(stream, qA2, kA2, sA2, nullptr, SS, ENCS, DD, 2 * BB,
          (long)SS * DD, (long)ENCS * DD, (long)SS * ENCS,
          nullptr, nullptr, nullptr, 0, 0, 0);
    softmax512_kernel<<<dim3(2 * NTOK / 4), dim3(256), 0, stream>>>(sA2, pA2, 0.03125f);
    // ctx = pA @ vAt^T  (batch 8)
    ggemm(stream, pA2, vAt2, nullptr, ctx2, SS, DD, ENCS, 2 * BB,
          (long)SS * ENCS, (long)DD * ENCS, (long)SS * DD,
          nullptr, nullptr, nullptr, 0, 0, 0);
    // hA[e] = x1 + ctx[e] @ Wo[e]  (batch 2)
    ggemm(stream, ctx2, wo2, nullptr, hA2, NTOK, DD, DD, 2,
          (long)NTOK * DD, (long)DD * DD, (long)NTOK * DD,
          nullptr, f_x1, nullptr, 0, 0, 0);

    // 14) all-expert sparse FFN, fully batched
    CONVTB(eaW1, w1a, DD, DFE, 2);                       // experts 0,1
    CONVTB(ebW1, w1a + 2 * W1SZ, DD, DFE, 2);            // experts 2,3
    CONVTB(ebW1 + 2 * W1SZ, w1b, DD, DFE, 4);            // experts 4-7
    CONVTB(eaW2, w2a, DFE, DD, 2);
    CONVTB(ebW2, w2a + 2 * W1SZ, DFE, DD, 2);
    CONVTB(ebW2 + 2 * W1SZ, w2b, DFE, DD, 4);
    moe_w1<<<dim3(DFE / 128, NTOK / 128, NE), dim3(256), 0, stream>>>(
        hA2, u_x1, w1a, w1b, ffpool, moe_idx, moe_cnt, moe_offp, DFE, DD);
    moe_w2<<<dim3(DD / 128, NTOK / 128, NE), dim3(256), 0, stream>>>(
        ffpool, w2a, w2b, out, moe_idx, moe_gv, moe_cnt, moe_offp, DD, DFE);
    (void)in_sizes; (void)n_in; (void)out_size; (void)ws_size;
}